// Round 1
// baseline (1152.719 us; speedup 1.0000x reference)
//
#include <hip/hip_runtime.h>
#include <hip/hip_bf16.h>

// ============================================================================
// MSARowAttentionWithPairBias (S=256,R=256,C=256,H=8,d=32) — MI355X gfx950
// Round 1: correct fp32-VALU baseline; bf16 intermediates in workspace.
//
// ws layout (bytes), requires ws_size >= ~170MB:
//   [0,        33554432)  m bf16 [65536][256]   (reused as gwa after k_qkvg)
//   [33554432, 35651584)  nb_bias f32 [8][256][256]
//   [35651584, ...     )  q,k,v,gate bf16, each [(S*H)=2048][256][32]
// ============================================================================

typedef unsigned short u16;
typedef unsigned int   u32;

__device__ __forceinline__ float bf2f(u16 u){
  union { u32 i; float f; } v; v.i = ((u32)u) << 16; return v.f;
}
__device__ __forceinline__ u16 f2bf(float f){
  union { float f; u32 i; } v; v.f = f;
  u32 x = v.i;
  return (u16)((x + 0x7fffu + ((x >> 16) & 1u)) >> 16);  // RNE
}
__device__ __forceinline__ void unpack8(uint4 t, float* f){
  f[0] = bf2f((u16)(t.x & 0xffffu)); f[1] = bf2f((u16)(t.x >> 16));
  f[2] = bf2f((u16)(t.y & 0xffffu)); f[3] = bf2f((u16)(t.y >> 16));
  f[4] = bf2f((u16)(t.z & 0xffffu)); f[5] = bf2f((u16)(t.z >> 16));
  f[6] = bf2f((u16)(t.w & 0xffffu)); f[7] = bf2f((u16)(t.w >> 16));
}

// ---------------------------------------------------------------------------
// K0: LayerNorm of msa_act rows (C=256) -> m bf16.  wave-per-row, 4 rows/block
// ---------------------------------------------------------------------------
__global__ __launch_bounds__(256) void k_ln_msa(
    const float* __restrict__ x, const float* __restrict__ sc,
    const float* __restrict__ of, u16* __restrict__ mo)
{
  const int lane = threadIdx.x & 63;
  const int row  = (blockIdx.x << 2) + (threadIdx.x >> 6);
  float4 v = ((const float4*)(x + (size_t)row * 256))[lane];
  float s  = v.x + v.y + v.z + v.w;
  float s2 = v.x*v.x + v.y*v.y + v.z*v.z + v.w*v.w;
  #pragma unroll
  for (int o = 32; o > 0; o >>= 1){ s += __shfl_xor(s, o); s2 += __shfl_xor(s2, o); }
  const float mu = s * (1.0f/256.0f);
  const float rs = rsqrtf(s2 * (1.0f/256.0f) - mu*mu + 1e-5f);
  float4 scv = ((const float4*)sc)[lane];
  float4 ofv = ((const float4*)of)[lane];
  u32 p0 = (u32)f2bf((v.x-mu)*rs*scv.x + ofv.x) | ((u32)f2bf((v.y-mu)*rs*scv.y + ofv.y) << 16);
  u32 p1 = (u32)f2bf((v.z-mu)*rs*scv.z + ofv.z) | ((u32)f2bf((v.w-mu)*rs*scv.w + ofv.w) << 16);
  ((uint2*)(mo + (size_t)row * 256))[lane] = make_uint2(p0, p1);
}

// ---------------------------------------------------------------------------
// K1: LayerNorm of pair_act rows (Cz=128) + nb_bias[h][q][k] = p . w2d[:,h]
// wave-per-(q,k) row
// ---------------------------------------------------------------------------
__global__ __launch_bounds__(256) void k_ln_pair(
    const float* __restrict__ p, const float* __restrict__ sc,
    const float* __restrict__ of, const float* __restrict__ w2d,
    float* __restrict__ nb)
{
  const int lane = threadIdx.x & 63;
  const int row  = (blockIdx.x << 2) + (threadIdx.x >> 6);  // q*256 + k
  float2 v = ((const float2*)(p + (size_t)row * 128))[lane];
  float s = v.x + v.y, s2 = v.x*v.x + v.y*v.y;
  #pragma unroll
  for (int o = 32; o > 0; o >>= 1){ s += __shfl_xor(s, o); s2 += __shfl_xor(s2, o); }
  const float mu = s * (1.0f/128.0f);
  const float rs = rsqrtf(s2 * (1.0f/128.0f) - mu*mu + 1e-5f);
  const int c0 = lane * 2;
  const float y0 = (v.x - mu) * rs * sc[c0]     + of[c0];
  const float y1 = (v.y - mu) * rs * sc[c0 + 1] + of[c0 + 1];
  const float4* w0 = (const float4*)(w2d + c0 * 8);
  const float4* w1 = (const float4*)(w2d + (c0 + 1) * 8);
  float4 a0 = w0[0], b0 = w0[1], a1 = w1[0], b1 = w1[1];
  float ph[8];
  ph[0] = y0*a0.x + y1*a1.x; ph[1] = y0*a0.y + y1*a1.y;
  ph[2] = y0*a0.z + y1*a1.z; ph[3] = y0*a0.w + y1*a1.w;
  ph[4] = y0*b0.x + y1*b1.x; ph[5] = y0*b0.y + y1*b1.y;
  ph[6] = y0*b0.z + y1*b1.z; ph[7] = y0*b0.w + y1*b1.w;
  #pragma unroll
  for (int o = 32; o > 0; o >>= 1){
    #pragma unroll
    for (int hh = 0; hh < 8; hh++) ph[hh] += __shfl_xor(ph[hh], o);
  }
  if (lane == 0){
    #pragma unroll
    for (int hh = 0; hh < 8; hh++) nb[(size_t)hh * 65536 + row] = ph[hh];
  }
}

// ---------------------------------------------------------------------------
// K2: QKVG projection GEMM. M=65536 (b,q), N=1024 (q|k|v|gate x 256), K=256.
// A = m bf16, B = weight f32. 128x128 block tile, BK=32, 8x8 per thread.
// LDS granule XOR-swizzle (granule ^ (k&7)) => conflict-free stage + read.
// Epilogue: q scaled 1/sqrt(32); gate -> sigmoid(x + gating_b).
// Output layout per matrix: [(b*8+h)][r][c] bf16 (attention-tile contiguous).
// ---------------------------------------------------------------------------
__global__ __launch_bounds__(256) void k_qkvg(
    const u16* __restrict__ m,
    const float* __restrict__ qw, const float* __restrict__ kw,
    const float* __restrict__ vw, const float* __restrict__ gw,
    const float* __restrict__ gb,
    u16* __restrict__ qo, u16* __restrict__ ko,
    u16* __restrict__ vo, u16* __restrict__ go)
{
  __shared__ float As[32 * 128];
  __shared__ float Bs[32 * 128];
  const int by = blockIdx.x & 7;
  const int bx = blockIdx.x >> 3;
  const int row0  = bx << 7;
  const int col0  = by << 7;            // global col 0..1023
  const int mat   = col0 >> 8;          // 0=q 1=k 2=v 3=gate
  const int wcol0 = col0 & 255;
  const float* W = (mat == 0) ? qw : (mat == 1) ? kw : (mat == 2) ? vw : gw;
  u16* O         = (mat == 0) ? qo : (mat == 1) ? ko : (mat == 2) ? vo : go;
  const int tid = threadIdx.x;
  const int tr = tid >> 4, tc = tid & 15;

  float acc[8][8];
  #pragma unroll
  for (int i = 0; i < 8; i++)
    #pragma unroll
    for (int j = 0; j < 8; j++) acc[i][j] = 0.0f;

  const int sr  = tid >> 1;             // A-stage row 0..127
  const int shk = (tid & 1) << 4;       // A-stage k offset 0/16
  const int bk  = tid >> 3;             // B-stage k 0..31
  const int bj4 = (tid & 7) << 2;       // B-stage granule base

  #pragma unroll 1
  for (int k0 = 0; k0 < 256; k0 += 32){
    { // stage A: bf16 -> f32, As[k][r] with swizzled granules
      const uint4* src = (const uint4*)(m + (size_t)(row0 + sr) * 256 + k0 + shk);
      uint4 d0 = src[0], d1 = src[1];
      u32 uu[8] = {d0.x, d0.y, d0.z, d0.w, d1.x, d1.y, d1.z, d1.w};
      #pragma unroll
      for (int i = 0; i < 8; i++){
        const int ke = shk + 2*i;              // (ke&7)==(2i)&7 for both halves
        const int cp0 = (((sr >> 2) ^ ((2*i    ) & 7)) << 2) + (sr & 3);
        const int cp1 = (((sr >> 2) ^ ((2*i + 1) & 7)) << 2) + (sr & 3);
        As[(ke    ) * 128 + cp0] = bf2f((u16)(uu[i] & 0xffffu));
        As[(ke + 1) * 128 + cp1] = bf2f((u16)(uu[i] >> 16));
      }
    }
    { // stage B: f32, Bs[k][j] with swizzled granules
      const float4* src = (const float4*)(W + (size_t)(k0 + bk) * 256 + wcol0 + (bj4 << 2));
      #pragma unroll
      for (int i = 0; i < 4; i++){
        const int jg = bj4 + i;
        *(float4*)&Bs[bk * 128 + ((jg ^ (bk & 7)) << 2)] = src[i];
      }
    }
    __syncthreads();
    #pragma unroll 8
    for (int k = 0; k < 32; k++){
      const int swk = k & 7;
      float a[8], b[8];
      *(float4*)&a[0] = *(const float4*)&As[k * 128 + (((tr*2    ) ^ swk) << 2)];
      *(float4*)&a[4] = *(const float4*)&As[k * 128 + (((tr*2 + 1) ^ swk) << 2)];
      *(float4*)&b[0] = *(const float4*)&Bs[k * 128 + (((tc*2    ) ^ swk) << 2)];
      *(float4*)&b[4] = *(const float4*)&Bs[k * 128 + (((tc*2 + 1) ^ swk) << 2)];
      #pragma unroll
      for (int i = 0; i < 8; i++)
        #pragma unroll
        for (int j = 0; j < 8; j++)
          acc[i][j] = fmaf(a[i], b[j], acc[i][j]);
    }
    __syncthreads();
  }

  // epilogue
  const int colg = wcol0 + (tc << 3);
  const int h = colg >> 5, c0 = colg & 31;
  float gbv[8];
  if (mat == 3){
    #pragma unroll
    for (int j = 0; j < 8; j++) gbv[j] = gb[(h << 5) + c0 + j];
  }
  #pragma unroll
  for (int i = 0; i < 8; i++){
    const int row = row0 + tr * 8 + i;
    const int bb = row >> 8, qr = row & 255;
    float vals[8];
    #pragma unroll
    for (int j = 0; j < 8; j++) vals[j] = acc[i][j];
    if (mat == 0){
      #pragma unroll
      for (int j = 0; j < 8; j++) vals[j] *= 0.17677669529663687f;  // 32^-0.5
    } else if (mat == 3){
      #pragma unroll
      for (int j = 0; j < 8; j++) vals[j] = 1.0f / (1.0f + __expf(-(vals[j] + gbv[j])));
    }
    u32 pk[4];
    #pragma unroll
    for (int jj = 0; jj < 4; jj++)
      pk[jj] = (u32)f2bf(vals[2*jj]) | ((u32)f2bf(vals[2*jj + 1]) << 16);
    *(uint4*)(O + ((size_t)((bb << 3) + h) * 256 + qr) * 32 + c0) =
        make_uint4(pk[0], pk[1], pk[2], pk[3]);
  }
}

// ---------------------------------------------------------------------------
// K3: attention per (b,h). thread = q-row. K/V staged f32 in swizzled LDS
// (broadcast reads in dot/PV). Online softmax in 16-wide chunks.
// Applies mask bias + nb_bias, then gate; writes gwa bf16 [b*256+q][h*32+c].
// ---------------------------------------------------------------------------
__global__ __launch_bounds__(256) void k_attn(
    const u16* __restrict__ qp, const u16* __restrict__ kp,
    const u16* __restrict__ vp, const u16* __restrict__ gp,
    const int* __restrict__ mask, const float* __restrict__ nb,
    u16* __restrict__ gwa)
{
  __shared__ float Ksh[8192];
  __shared__ float Vsh[8192];
  __shared__ float maskb[256];
  const int blk = blockIdx.x;
  const int b = blk >> 3, h = blk & 7;
  const int tid = threadIdx.x;
  const size_t tbase = (size_t)blk * 8192;     // (b*8+h)*256*32

  { // stage K, V tiles (16KB bf16 each) -> f32 LDS, swizzled granules
    const uint4* ks = (const uint4*)(kp + tbase);
    const uint4* vs = (const uint4*)(vp + tbase);
    #pragma unroll
    for (int i = 0; i < 4; i++){
      uint4 kq = ks[i * 256 + tid];
      uint4 vq = vs[i * 256 + tid];
      const int kr = i * 64 + (tid >> 2);
      const int g0 = (tid & 3) * 2;
      const int sw = kr & 7;
      const int base0 = kr * 32 + (((g0    ) ^ sw) << 2);
      const int base1 = kr * 32 + (((g0 + 1) ^ sw) << 2);
      float tk[8], tv[8];
      unpack8(kq, tk); unpack8(vq, tv);
      *(float4*)&Ksh[base0] = make_float4(tk[0], tk[1], tk[2], tk[3]);
      *(float4*)&Ksh[base1] = make_float4(tk[4], tk[5], tk[6], tk[7]);
      *(float4*)&Vsh[base0] = make_float4(tv[0], tv[1], tv[2], tv[3]);
      *(float4*)&Vsh[base1] = make_float4(tv[4], tv[5], tv[6], tv[7]);
    }
  }
  maskb[tid] = 1e9f * ((float)mask[(b << 8) + tid] - 1.0f);

  float qv[32];
  {
    const uint4* qs = (const uint4*)(qp + tbase + (size_t)tid * 32);
    #pragma unroll
    for (int i = 0; i < 4; i++){ uint4 t = qs[i]; unpack8(t, &qv[i * 8]); }
  }
  __syncthreads();

  float o[32];
  #pragma unroll
  for (int c = 0; c < 32; c++) o[c] = 0.0f;
  float mrun = -1e30f, lrun = 0.0f;
  const float* nbrow = nb + (size_t)h * 65536 + (size_t)tid * 256;

  #pragma unroll 1
  for (int kc = 0; kc < 256; kc += 16){
    float nbv[16];
    {
      const float4* p4 = (const float4*)(nbrow + kc);
      float4 t0 = p4[0], t1 = p4[1], t2 = p4[2], t3 = p4[3];
      nbv[0]=t0.x;  nbv[1]=t0.y;  nbv[2]=t0.z;  nbv[3]=t0.w;
      nbv[4]=t1.x;  nbv[5]=t1.y;  nbv[6]=t1.z;  nbv[7]=t1.w;
      nbv[8]=t2.x;  nbv[9]=t2.y;  nbv[10]=t2.z; nbv[11]=t2.w;
      nbv[12]=t3.x; nbv[13]=t3.y; nbv[14]=t3.z; nbv[15]=t3.w;
    }
    float s[16];
    #pragma unroll
    for (int j = 0; j < 16; j++){
      const int kr = kc + j;
      const int sw = j & 7;                    // == kr&7 (kc%16==0)
      float acc = 0.0f;
      #pragma unroll
      for (int gg = 0; gg < 8; gg++){
        const float4 kf = *(const float4*)&Ksh[kr * 32 + ((gg ^ sw) << 2)];
        acc = fmaf(qv[gg*4+0], kf.x, acc);
        acc = fmaf(qv[gg*4+1], kf.y, acc);
        acc = fmaf(qv[gg*4+2], kf.z, acc);
        acc = fmaf(qv[gg*4+3], kf.w, acc);
      }
      s[j] = acc + maskb[kr] + nbv[j];
    }
    float cmax = s[0];
    #pragma unroll
    for (int j = 1; j < 16; j++) cmax = fmaxf(cmax, s[j]);
    const float mnew = fmaxf(mrun, cmax);
    const float corr = __expf(mrun - mnew);
    lrun *= corr;
    #pragma unroll
    for (int c = 0; c < 32; c++) o[c] *= corr;
    #pragma unroll
    for (int j = 0; j < 16; j++){
      const int kr = kc + j;
      const int sw = j & 7;
      const float pw = __expf(s[j] - mnew);
      lrun += pw;
      #pragma unroll
      for (int gg = 0; gg < 8; gg++){
        const float4 vf = *(const float4*)&Vsh[kr * 32 + ((gg ^ sw) << 2)];
        o[gg*4+0] = fmaf(pw, vf.x, o[gg*4+0]);
        o[gg*4+1] = fmaf(pw, vf.y, o[gg*4+1]);
        o[gg*4+2] = fmaf(pw, vf.z, o[gg*4+2]);
        o[gg*4+3] = fmaf(pw, vf.w, o[gg*4+3]);
      }
    }
    mrun = mnew;
  }
  const float inv = 1.0f / lrun;

  float gv[32];
  {
    const uint4* gs = (const uint4*)(gp + tbase + (size_t)tid * 32);
    #pragma unroll
    for (int i = 0; i < 4; i++){ uint4 t = gs[i]; unpack8(t, &gv[i * 8]); }
  }
  u32 opk[16];
  #pragma unroll
  for (int jj = 0; jj < 16; jj++){
    const float x0 = o[2*jj]     * inv * gv[2*jj];
    const float x1 = o[2*jj + 1] * inv * gv[2*jj + 1];
    opk[jj] = (u32)f2bf(x0) | ((u32)f2bf(x1) << 16);
  }
  u16* dst = gwa + ((size_t)((b << 8) + tid)) * 256 + (h << 5);
  ((uint4*)dst)[0] = make_uint4(opk[0],  opk[1],  opk[2],  opk[3]);
  ((uint4*)dst)[1] = make_uint4(opk[4],  opk[5],  opk[6],  opk[7]);
  ((uint4*)dst)[2] = make_uint4(opk[8],  opk[9],  opk[10], opk[11]);
  ((uint4*)dst)[3] = make_uint4(opk[12], opk[13], opk[14], opk[15]);
}

// ---------------------------------------------------------------------------
// K4: output projection. out[b*256+q][o] = sum_hc gwa[row][hc]*ow[hc][o] + ob
// M=65536, N=256, K=256. Same GEMM structure as k_qkvg. f32 output.
// ---------------------------------------------------------------------------
__global__ __launch_bounds__(256) void k_out(
    const u16* __restrict__ a, const float* __restrict__ w,
    const float* __restrict__ bias, float* __restrict__ out)
{
  __shared__ float As[32 * 128];
  __shared__ float Bs[32 * 128];
  const int by = blockIdx.x & 1;
  const int bx = blockIdx.x >> 1;
  const int row0 = bx << 7;
  const int col0 = by << 7;
  const int tid = threadIdx.x;
  const int tr = tid >> 4, tc = tid & 15;

  float acc[8][8];
  #pragma unroll
  for (int i = 0; i < 8; i++)
    #pragma unroll
    for (int j = 0; j < 8; j++) acc[i][j] = 0.0f;

  const int sr  = tid >> 1;
  const int shk = (tid & 1) << 4;
  const int bk  = tid >> 3;
  const int bj4 = (tid & 7) << 2;

  #pragma unroll 1
  for (int k0 = 0; k0 < 256; k0 += 32){
    {
      const uint4* src = (const uint4*)(a + (size_t)(row0 + sr) * 256 + k0 + shk);
      uint4 d0 = src[0], d1 = src[1];
      u32 uu[8] = {d0.x, d0.y, d0.z, d0.w, d1.x, d1.y, d1.z, d1.w};
      #pragma unroll
      for (int i = 0; i < 8; i++){
        const int ke = shk + 2*i;
        const int cp0 = (((sr >> 2) ^ ((2*i    ) & 7)) << 2) + (sr & 3);
        const int cp1 = (((sr >> 2) ^ ((2*i + 1) & 7)) << 2) + (sr & 3);
        As[(ke    ) * 128 + cp0] = bf2f((u16)(uu[i] & 0xffffu));
        As[(ke + 1) * 128 + cp1] = bf2f((u16)(uu[i] >> 16));
      }
    }
    {
      const float4* src = (const float4*)(w + (size_t)(k0 + bk) * 256 + col0 + (bj4 << 2));
      #pragma unroll
      for (int i = 0; i < 4; i++){
        const int jg = bj4 + i;
        *(float4*)&Bs[bk * 128 + ((jg ^ (bk & 7)) << 2)] = src[i];
      }
    }
    __syncthreads();
    #pragma unroll 8
    for (int k = 0; k < 32; k++){
      const int swk = k & 7;
      float av[8], bv[8];
      *(float4*)&av[0] = *(const float4*)&As[k * 128 + (((tr*2    ) ^ swk) << 2)];
      *(float4*)&av[4] = *(const float4*)&As[k * 128 + (((tr*2 + 1) ^ swk) << 2)];
      *(float4*)&bv[0] = *(const float4*)&Bs[k * 128 + (((tc*2    ) ^ swk) << 2)];
      *(float4*)&bv[4] = *(const float4*)&Bs[k * 128 + (((tc*2 + 1) ^ swk) << 2)];
      #pragma unroll
      for (int i = 0; i < 8; i++)
        #pragma unroll
        for (int j = 0; j < 8; j++)
          acc[i][j] = fmaf(av[i], bv[j], acc[i][j]);
    }
    __syncthreads();
  }

  float bvs[8];
  #pragma unroll
  for (int j = 0; j < 8; j++) bvs[j] = bias[col0 + tc * 8 + j];
  #pragma unroll
  for (int i = 0; i < 8; i++){
    const int row = row0 + tr * 8 + i;
    float* dst = out + (size_t)row * 256 + col0 + tc * 8;
    ((float4*)dst)[0] = make_float4(acc[i][0]+bvs[0], acc[i][1]+bvs[1],
                                    acc[i][2]+bvs[2], acc[i][3]+bvs[3]);
    ((float4*)dst)[1] = make_float4(acc[i][4]+bvs[4], acc[i][5]+bvs[5],
                                    acc[i][6]+bvs[6], acc[i][7]+bvs[7]);
  }
}

// ---------------------------------------------------------------------------
extern "C" void kernel_launch(void* const* d_in, const int* in_sizes, int n_in,
                              void* d_out, int out_size, void* d_ws, size_t ws_size,
                              hipStream_t stream)
{
  (void)in_sizes; (void)n_in; (void)out_size; (void)ws_size;
  const float* msa  = (const float*)d_in[0];
  const int*   mask = (const int*)  d_in[1];
  const float* pair = (const float*)d_in[2];
  const float* qns  = (const float*)d_in[3];
  const float* qno  = (const float*)d_in[4];
  const float* pns  = (const float*)d_in[5];
  const float* pno  = (const float*)d_in[6];
  const float* w2d  = (const float*)d_in[7];
  const float* qw   = (const float*)d_in[8];
  const float* kw   = (const float*)d_in[9];
  const float* vw   = (const float*)d_in[10];
  const float* ow   = (const float*)d_in[11];
  const float* ob   = (const float*)d_in[12];
  const float* gw   = (const float*)d_in[13];
  const float* gb   = (const float*)d_in[14];
  float* out = (float*)d_out;

  char* ws = (char*)d_ws;
  u16*   m_ws = (u16*)ws;                          // 33,554,432 B (also gwa)
  float* nb   = (float*)(ws + 33554432);           //  2,097,152 B
  u16*   q_ws = (u16*)(ws + 35651584);             // 33,554,432 B each:
  u16*   k_ws = q_ws + 16777216;
  u16*   v_ws = k_ws + 16777216;
  u16*   g_ws = v_ws + 16777216;
  u16*   gwa  = m_ws;                              // reuse m after k_qkvg

  k_ln_msa <<<16384, 256, 0, stream>>>(msa, qns, qno, m_ws);
  k_ln_pair<<<16384, 256, 0, stream>>>(pair, pns, pno, w2d, nb);
  k_qkvg   <<< 4096, 256, 0, stream>>>(m_ws, qw, kw, vw, gw, gb, q_ws, k_ws, v_ws, g_ws);
  k_attn   <<< 2048, 256, 0, stream>>>(q_ws, k_ws, v_ws, g_ws, mask, nb, gwa);
  k_out    <<< 1024, 256, 0, stream>>>(gwa, ow, ob, out);
}

// Round 3
// 592.794 us; speedup vs baseline: 1.9446x; 1.9446x over previous
//
#include <hip/hip_runtime.h>
#include <hip/hip_bf16.h>
#include <stdint.h>

// ============================================================================
// MSARowAttentionWithPairBias (S=256,R=256,C=256,H=8,d=32) — MI355X gfx950
// Round 2 (resubmit after GPU acquisition timeout): bf16 MFMA (16x16x32) for
// QKVG GEMM, attention, and output GEMM.
//
// ws layout (bytes):
//   [0,         33554432)  m bf16 [65536][256]      (reused as gwa after attn)
//   [33554432,  35651584)  nb f32 [8][256][256]
//   [35651584,  69206016)  q  bf16 [(b*8+h)][256 r][32 c]   (pre-scaled)
//   [69206016, 102760448)  k  bf16 [(b*8+h)][256 r][32 c]
//   [102760448,136314880)  vT bf16 [(b*8+h)][32 c][256 r]   (transposed!)
//   [136314880,169869312)  g  bf16 [(b*8+h)][256 r][32 c]   (sigmoid applied)
//   [169869312,170524672)  wT bf16 [5][256 n][256 k]  (q,k,v,gate,o transposed)
// ============================================================================

typedef unsigned short u16;
typedef unsigned int   u32;
typedef __attribute__((ext_vector_type(8))) short bf16x8;
typedef __attribute__((ext_vector_type(4))) float f32x4;

__device__ __forceinline__ float bf2f(u16 u){ union { u32 i; float f; } v; v.i = ((u32)u)<<16; return v.f; }
__device__ __forceinline__ u16 f2bf(float f){
  union { float f; u32 i; } v; v.f = f; u32 x = v.i;
  return (u16)((x + 0x7fffu + ((x>>16)&1u)) >> 16);
}
__device__ __forceinline__ u32 pk2(float a, float b){ return (u32)f2bf(a) | ((u32)f2bf(b) << 16); }

__device__ __forceinline__ void gl_lds16(const void* g, void* l){
  __builtin_amdgcn_global_load_lds(
    reinterpret_cast<const __attribute__((address_space(1))) unsigned int*>(reinterpret_cast<uintptr_t>(g)),
    reinterpret_cast<__attribute__((address_space(3))) unsigned int*>(reinterpret_cast<uintptr_t>(l)),
    16, 0, 0);
}

// ---------------------------------------------------------------------------
// K0: LayerNorm msa rows (C=256) -> m bf16. (unchanged from round 1)
// ---------------------------------------------------------------------------
__global__ __launch_bounds__(256) void k_ln_msa(
    const float* __restrict__ x, const float* __restrict__ sc,
    const float* __restrict__ of, u16* __restrict__ mo)
{
  const int lane = threadIdx.x & 63;
  const int row  = (blockIdx.x << 2) + (threadIdx.x >> 6);
  float4 v = ((const float4*)(x + (size_t)row * 256))[lane];
  float s  = v.x + v.y + v.z + v.w;
  float s2 = v.x*v.x + v.y*v.y + v.z*v.z + v.w*v.w;
  #pragma unroll
  for (int o = 32; o > 0; o >>= 1){ s += __shfl_xor(s, o); s2 += __shfl_xor(s2, o); }
  const float mu = s * (1.0f/256.0f);
  const float rs = rsqrtf(s2 * (1.0f/256.0f) - mu*mu + 1e-5f);
  float4 scv = ((const float4*)sc)[lane];
  float4 ofv = ((const float4*)of)[lane];
  u32 p0 = pk2((v.x-mu)*rs*scv.x + ofv.x, (v.y-mu)*rs*scv.y + ofv.y);
  u32 p1 = pk2((v.z-mu)*rs*scv.z + ofv.z, (v.w-mu)*rs*scv.w + ofv.w);
  ((uint2*)(mo + (size_t)row * 256))[lane] = make_uint2(p0, p1);
}

// ---------------------------------------------------------------------------
// K1: LayerNorm pair rows (Cz=128) + nb[h][q][k]. (unchanged from round 1)
// ---------------------------------------------------------------------------
__global__ __launch_bounds__(256) void k_ln_pair(
    const float* __restrict__ p, const float* __restrict__ sc,
    const float* __restrict__ of, const float* __restrict__ w2d,
    float* __restrict__ nb)
{
  const int lane = threadIdx.x & 63;
  const int row  = (blockIdx.x << 2) + (threadIdx.x >> 6);
  float2 v = ((const float2*)(p + (size_t)row * 128))[lane];
  float s = v.x + v.y, s2 = v.x*v.x + v.y*v.y;
  #pragma unroll
  for (int o = 32; o > 0; o >>= 1){ s += __shfl_xor(s, o); s2 += __shfl_xor(s2, o); }
  const float mu = s * (1.0f/128.0f);
  const float rs = rsqrtf(s2 * (1.0f/128.0f) - mu*mu + 1e-5f);
  const int c0 = lane * 2;
  const float y0 = (v.x - mu) * rs * sc[c0]     + of[c0];
  const float y1 = (v.y - mu) * rs * sc[c0 + 1] + of[c0 + 1];
  const float4* w0 = (const float4*)(w2d + c0 * 8);
  const float4* w1 = (const float4*)(w2d + (c0 + 1) * 8);
  float4 a0 = w0[0], b0 = w0[1], a1 = w1[0], b1 = w1[1];
  float ph[8];
  ph[0] = y0*a0.x + y1*a1.x; ph[1] = y0*a0.y + y1*a1.y;
  ph[2] = y0*a0.z + y1*a1.z; ph[3] = y0*a0.w + y1*a1.w;
  ph[4] = y0*b0.x + y1*b1.x; ph[5] = y0*b0.y + y1*b1.y;
  ph[6] = y0*b0.z + y1*b1.z; ph[7] = y0*b0.w + y1*b1.w;
  #pragma unroll
  for (int o = 32; o > 0; o >>= 1){
    #pragma unroll
    for (int hh = 0; hh < 8; hh++) ph[hh] += __shfl_xor(ph[hh], o);
  }
  if (lane == 0){
    #pragma unroll
    for (int hh = 0; hh < 8; hh++) nb[(size_t)hh * 65536 + row] = ph[hh];
  }
}

// ---------------------------------------------------------------------------
// K2: cast+transpose the 5 weight matrices (256x256 f32) -> wT[mat][n][k] bf16
// mat: 0=q 1=k 2=v 3=gate 4=o.  wT[n][k] = W[k][n].
// ---------------------------------------------------------------------------
__global__ __launch_bounds__(256) void k_cast(
    const float* __restrict__ qw, const float* __restrict__ kw,
    const float* __restrict__ vw, const float* __restrict__ gw,
    const float* __restrict__ ow, u16* __restrict__ wT)
{
  const int mt = blockIdx.x >> 4;
  const float* src = (mt == 0) ? qw : (mt == 1) ? kw : (mt == 2) ? vw : (mt == 3) ? gw : ow;
  u16* dst = wT + mt * 65536;
  const int tid = threadIdx.x;
  const int n  = ((blockIdx.x & 15) << 4) + (tid & 15);
  const int kc = tid >> 4;
  float v[16];
  #pragma unroll
  for (int kk = 0; kk < 16; kk++) v[kk] = src[(kc*16 + kk)*256 + n];
  #pragma unroll
  for (int p = 0; p < 8; p++)
    *(u32*)&dst[n*256 + kc*16 + 2*p] = pk2(v[2*p], v[2*p+1]);
}

// ---------------------------------------------------------------------------
// K3: QKVG projection GEMM, bf16 MFMA. M=65536, N=1024(4x256), K=256.
// 128x128 tile, BK=64, 4 waves (2x2), 4x4 16x16 frags each.
// LDS subtiled [r/16][kg][16 r][8 k(16B)] -> conflict-free frag reads; staged
// via global_load_lds w16 with pre-decoded per-lane source.
// Epilogue: q *= 1/sqrt(32); gate = sigmoid(+gb); V stored TRANSPOSED.
// ---------------------------------------------------------------------------
__global__ __launch_bounds__(256) void k_qkvg(
    const u16* __restrict__ m, const u16* __restrict__ wT, const float* __restrict__ gb,
    u16* __restrict__ qo, u16* __restrict__ ko, u16* __restrict__ vTo, u16* __restrict__ go)
{
  __shared__ __align__(16) u16 As[8192];
  __shared__ __align__(16) u16 Bs[8192];
  const int tid = threadIdx.x;
  const int w = tid >> 6, lane = tid & 63, g = lane >> 4, q16 = lane & 15;
  const int by = blockIdx.x & 7, bx = blockIdx.x >> 3;
  const int row0  = bx << 7;
  const int mat   = by >> 1;
  const int ncol0 = (by & 1) << 7;
  const u16* Wt = wT + mat * 65536;
  const int wr = w >> 1, wc = w & 1;

  const int rA  = ((tid >> 7) << 4) + (tid & 15);   // stage row, + c*32
  const int kgA = (tid >> 4) & 7;                   // stage k-granule

  const f32x4 z4 = {0.f, 0.f, 0.f, 0.f};
  f32x4 acc[4][4];
  #pragma unroll
  for (int i = 0; i < 4; i++)
    #pragma unroll
    for (int j = 0; j < 4; j++) acc[i][j] = z4;

  #pragma unroll 1
  for (int ks = 0; ks < 4; ks++){
    const int k0 = ks << 6;
    #pragma unroll
    for (int c = 0; c < 4; c++){
      gl_lds16(m  + (size_t)(row0  + rA + c*32)*256 + k0 + kgA*8,
               (char*)As + c*4096 + w*1024);
      gl_lds16(Wt + (size_t)(ncol0 + rA + c*32)*256 + k0 + kgA*8,
               (char*)Bs + c*4096 + w*1024);
    }
    __syncthreads();
    #pragma unroll
    for (int kk = 0; kk < 2; kk++){
      bf16x8 af[4], bfr[4];
      #pragma unroll
      for (int i = 0; i < 4; i++){
        af[i]  = *(const bf16x8*)((const char*)As + (wr*4+i)*2048 + (kk*4+g)*256 + q16*16);
        bfr[i] = *(const bf16x8*)((const char*)Bs + (wc*4+i)*2048 + (kk*4+g)*256 + q16*16);
      }
      #pragma unroll
      for (int i = 0; i < 4; i++)
        #pragma unroll
        for (int j = 0; j < 4; j++)
          acc[i][j] = __builtin_amdgcn_mfma_f32_16x16x32_bf16(af[i], bfr[j], acc[i][j], 0, 0, 0);
    }
    __syncthreads();
  }

  const int b  = bx >> 1;
  const int rb = (row0 & 255) + wr*64 + 4*g;        // + i*16 + v
  const int cb0 = ncol0 + wc*64 + q16;              // + j*16  (0..255 in matrix)

  if (mat == 2){
    #pragma unroll
    for (int i = 0; i < 4; i++){
      const int r = rb + i*16;
      #pragma unroll
      for (int j = 0; j < 4; j++){
        const int col = cb0 + j*16;
        const int hh = col >> 5, cc = col & 31;
        u16* base = vTo + (size_t)(b*8 + hh)*8192 + cc*256 + r;
        *(u32*)base       = pk2(acc[i][j][0], acc[i][j][1]);
        *(u32*)(base + 2) = pk2(acc[i][j][2], acc[i][j][3]);
      }
    }
  } else {
    u16* O = (mat == 0) ? qo : (mat == 1) ? ko : go;
    #pragma unroll
    for (int i = 0; i < 4; i++){
      #pragma unroll
      for (int j = 0; j < 4; j++){
        const int col = cb0 + j*16;
        const int hh = col >> 5, cc = col & 31;
        f32x4 a = acc[i][j];
        if (mat == 0) a *= 0.17677669529663687f;
        #pragma unroll
        for (int v = 0; v < 4; v++){
          float x = a[v];
          if (mat == 3) x = 1.0f / (1.0f + __expf(-(x + gb[col])));
          O[(size_t)((b*8 + hh)*256 + rb + i*16 + v)*32 + cc] = f2bf(x);
        }
      }
    }
  }
}

// ---------------------------------------------------------------------------
// K4: attention per (b,h) block, 4 waves x 64 q-rows, bf16 MFMA.
// Swapped QK^T: S^T = mfma(K, Q) -> k-reduction is in-lane + shfl_xor(16,32).
// Full-S softmax (k=256 = 16 frags/lane), P via wave-private swizzled LDS,
// PV as O^T = mfma(V^T, P^T) with V pre-transposed in global.
// ---------------------------------------------------------------------------
__global__ __launch_bounds__(256) void k_attn(
    const u16* __restrict__ qp, const u16* __restrict__ kp, const u16* __restrict__ vTp,
    const u16* __restrict__ gp, const int* __restrict__ mask, const float* __restrict__ nb,
    u16* __restrict__ gwa)
{
  __shared__ __align__(16) u16 Ksh[8192];          // [r/16][dg][16 r][8 d]
  __shared__ __align__(16) u16 Vsh[8192];          // [c/16][kg 32][16 c][8 k]
  __shared__ __align__(16) u16 Psh[4][1024];       // per-wave [16 q][64 k], swizzled
  __shared__ float maskb[256];
  const int tid = threadIdx.x;
  const int w = tid >> 6, lane = tid & 63, g = lane >> 4, q16 = lane & 15;
  const int blk = blockIdx.x, b = blk >> 3, h = blk & 7;
  const size_t tb = (size_t)blk * 8192;

  #pragma unroll
  for (int c = 0; c < 4; c++){
    const int u = c*4 + w;
    gl_lds16(kp  + tb + (size_t)(u*16 + q16)*32 + g*8,
             (char*)Ksh + u*1024);
    gl_lds16(vTp + tb + (size_t)((u>>3)*16 + q16)*256 + ((u&7)*4 + g)*8,
             (char*)Vsh + u*1024);
  }
  maskb[tid] = 1e9f * ((float)mask[b*256 + tid] - 1.0f);
  __syncthreads();

  const float* nbh = nb + (size_t)h * 65536;
  const f32x4 z4 = {0.f, 0.f, 0.f, 0.f};

  #pragma unroll 1
  for (int j = 0; j < 4; j++){
    const int q = w*64 + j*16 + q16;
    const bf16x8 qf = *(const bf16x8*)(qp + tb + (size_t)q*32 + g*8);

    f32x4 S[16];
    #pragma unroll
    for (int n = 0; n < 16; n++){
      const bf16x8 kf = *(const bf16x8*)((const char*)Ksh + n*1024 + g*256 + q16*16);
      S[n] = __builtin_amdgcn_mfma_f32_16x16x32_bf16(kf, qf, z4, 0, 0, 0);
    }

    float mx = -3.0e38f;
    #pragma unroll
    for (int n = 0; n < 16; n++){
      const f32x4 nbv = *(const f32x4*)(nbh + (size_t)q*256 + n*16 + 4*g);
      const f32x4 mbv = *(const f32x4*)&maskb[n*16 + 4*g];
      S[n] += nbv + mbv;
      mx = fmaxf(mx, fmaxf(fmaxf(S[n][0], S[n][1]), fmaxf(S[n][2], S[n][3])));
    }
    mx = fmaxf(mx, __shfl_xor(mx, 16));
    mx = fmaxf(mx, __shfl_xor(mx, 32));

    float sum = 0.f;
    #pragma unroll
    for (int n = 0; n < 16; n++){
      #pragma unroll
      for (int v = 0; v < 4; v++){
        const float p = __expf(S[n][v] - mx);
        S[n][v] = p; sum += p;
      }
    }
    sum += __shfl_xor(sum, 16);
    sum += __shfl_xor(sum, 32);
    const float inv = 1.0f / sum;

    f32x4 O0 = z4, O1 = z4;
    #pragma unroll
    for (int t = 0; t < 4; t++){
      #pragma unroll
      for (int nn = 0; nn < 4; nn++){
        const int n = t*4 + nn;
        const int kg = nn*2 + (g >> 1);
        char* pb = (char*)Psh[w] + q16*128 + ((kg ^ (q16 & 7)) << 4) + ((g & 1) << 3);
        *(u32*)pb       = pk2(S[n][0], S[n][1]);
        *(u32*)(pb + 4) = pk2(S[n][2], S[n][3]);
      }
      bf16x8 pfr[2];
      #pragma unroll
      for (int kx = 0; kx < 2; kx++)
        pfr[kx] = *(const bf16x8*)((const char*)Psh[w] + q16*128 + (((kx*4 + g) ^ (q16 & 7)) << 4));
      #pragma unroll
      for (int kx = 0; kx < 2; kx++){
        const bf16x8 v0 = *(const bf16x8*)((const char*)Vsh +        (t*8 + kx*4 + g)*256 + q16*16);
        const bf16x8 v1 = *(const bf16x8*)((const char*)Vsh + 8192 + (t*8 + kx*4 + g)*256 + q16*16);
        O0 = __builtin_amdgcn_mfma_f32_16x16x32_bf16(v0, pfr[kx], O0, 0, 0, 0);
        O1 = __builtin_amdgcn_mfma_f32_16x16x32_bf16(v1, pfr[kx], O1, 0, 0, 0);
      }
    }

    // epilogue: lane holds O^T[c = ct*16 + 4g + v][q]
    const uint2 gvA = *(const uint2*)(gp + tb + (size_t)q*32 + 4*g);
    const uint2 gvB = *(const uint2*)(gp + tb + (size_t)q*32 + 16 + 4*g);
    const float ga0 = bf2f((u16)(gvA.x & 0xffffu)), ga1 = bf2f((u16)(gvA.x >> 16));
    const float ga2 = bf2f((u16)(gvA.y & 0xffffu)), ga3 = bf2f((u16)(gvA.y >> 16));
    const float gb0 = bf2f((u16)(gvB.x & 0xffffu)), gb1 = bf2f((u16)(gvB.x >> 16));
    const float gb2 = bf2f((u16)(gvB.y & 0xffffu)), gb3 = bf2f((u16)(gvB.y >> 16));
    u16* dst = gwa + (size_t)(b*256 + q)*256 + h*32 + 4*g;
    *(u32*)dst        = pk2(O0[0]*inv*ga0, O0[1]*inv*ga1);
    *(u32*)(dst + 2)  = pk2(O0[2]*inv*ga2, O0[3]*inv*ga3);
    *(u32*)(dst + 16) = pk2(O1[0]*inv*gb0, O1[1]*inv*gb1);
    *(u32*)(dst + 18) = pk2(O1[2]*inv*gb2, O1[3]*inv*gb3);
  }
}

// ---------------------------------------------------------------------------
// K5: output projection GEMM, bf16 MFMA. M=65536, N=256, K=256. f32 out + bias.
// ---------------------------------------------------------------------------
__global__ __launch_bounds__(256) void k_out(
    const u16* __restrict__ a, const u16* __restrict__ Wt, const float* __restrict__ ob,
    float* __restrict__ out)
{
  __shared__ __align__(16) u16 As[8192];
  __shared__ __align__(16) u16 Bs[8192];
  const int tid = threadIdx.x;
  const int w = tid >> 6, lane = tid & 63, g = lane >> 4, q16 = lane & 15;
  const int by = blockIdx.x & 1, bx = blockIdx.x >> 1;
  const int row0  = bx << 7;
  const int ncol0 = by << 7;
  const int wr = w >> 1, wc = w & 1;

  const int rA  = ((tid >> 7) << 4) + (tid & 15);
  const int kgA = (tid >> 4) & 7;

  const f32x4 z4 = {0.f, 0.f, 0.f, 0.f};
  f32x4 acc[4][4];
  #pragma unroll
  for (int i = 0; i < 4; i++)
    #pragma unroll
    for (int j = 0; j < 4; j++) acc[i][j] = z4;

  #pragma unroll 1
  for (int ks = 0; ks < 4; ks++){
    const int k0 = ks << 6;
    #pragma unroll
    for (int c = 0; c < 4; c++){
      gl_lds16(a  + (size_t)(row0  + rA + c*32)*256 + k0 + kgA*8,
               (char*)As + c*4096 + w*1024);
      gl_lds16(Wt + (size_t)(ncol0 + rA + c*32)*256 + k0 + kgA*8,
               (char*)Bs + c*4096 + w*1024);
    }
    __syncthreads();
    #pragma unroll
    for (int kk = 0; kk < 2; kk++){
      bf16x8 af[4], bfr[4];
      #pragma unroll
      for (int i = 0; i < 4; i++){
        af[i]  = *(const bf16x8*)((const char*)As + (wr*4+i)*2048 + (kk*4+g)*256 + q16*16);
        bfr[i] = *(const bf16x8*)((const char*)Bs + (wc*4+i)*2048 + (kk*4+g)*256 + q16*16);
      }
      #pragma unroll
      for (int i = 0; i < 4; i++)
        #pragma unroll
        for (int j = 0; j < 4; j++)
          acc[i][j] = __builtin_amdgcn_mfma_f32_16x16x32_bf16(af[i], bfr[j], acc[i][j], 0, 0, 0);
    }
    __syncthreads();
  }

  const int rb = row0 + wr*64 + 4*g;
  #pragma unroll
  for (int i = 0; i < 4; i++){
    #pragma unroll
    for (int j = 0; j < 4; j++){
      const int col = ncol0 + wc*64 + j*16 + q16;
      const float bias = ob[col];
      #pragma unroll
      for (int v = 0; v < 4; v++)
        out[(size_t)(rb + i*16 + v)*256 + col] = acc[i][j][v] + bias;
    }
  }
}

// ---------------------------------------------------------------------------
extern "C" void kernel_launch(void* const* d_in, const int* in_sizes, int n_in,
                              void* d_out, int out_size, void* d_ws, size_t ws_size,
                              hipStream_t stream)
{
  (void)in_sizes; (void)n_in; (void)out_size; (void)ws_size;
  const float* msa  = (const float*)d_in[0];
  const int*   mask = (const int*)  d_in[1];
  const float* pair = (const float*)d_in[2];
  const float* qns  = (const float*)d_in[3];
  const float* qno  = (const float*)d_in[4];
  const float* pns  = (const float*)d_in[5];
  const float* pno  = (const float*)d_in[6];
  const float* w2d  = (const float*)d_in[7];
  const float* qw   = (const float*)d_in[8];
  const float* kw   = (const float*)d_in[9];
  const float* vw   = (const float*)d_in[10];
  const float* ow   = (const float*)d_in[11];
  const float* ob   = (const float*)d_in[12];
  const float* gw   = (const float*)d_in[13];
  const float* gb   = (const float*)d_in[14];
  float* out = (float*)d_out;

  char* ws = (char*)d_ws;
  u16*   m_ws = (u16*)ws;                          // 33,554,432 B (also gwa)
  float* nb   = (float*)(ws + 33554432);           //  2,097,152 B
  u16*   q_ws = (u16*)(ws + 35651584);
  u16*   k_ws = q_ws + 16777216;
  u16*   vT_ws= k_ws + 16777216;
  u16*   g_ws = vT_ws + 16777216;
  u16*   wT   = (u16*)(ws + 169869312);            // 655,360 B
  u16*   gwa  = m_ws;

  k_ln_msa <<<16384, 256, 0, stream>>>(msa, qns, qno, m_ws);
  k_ln_pair<<<16384, 256, 0, stream>>>(pair, pns, pno, w2d, nb);
  k_cast   <<<   80, 256, 0, stream>>>(qw, kw, vw, gw, ow, wT);
  k_qkvg   <<< 4096, 256, 0, stream>>>(m_ws, wT, gb, q_ws, k_ws, vT_ws, g_ws);
  k_attn   <<< 2048, 256, 0, stream>>>(q_ws, k_ws, vT_ws, g_ws, mask, nb, gwa);
  k_out    <<< 1024, 256, 0, stream>>>(gwa, wT + 4*65536, ob, out);
}

// Round 4
// 489.425 us; speedup vs baseline: 2.3553x; 1.2112x over previous
//
#include <hip/hip_runtime.h>
#include <hip/hip_bf16.h>
#include <stdint.h>

// ============================================================================
// MSARowAttentionWithPairBias (S=256,R=256,C=256,H=8,d=32) — MI355X gfx950
// Round 4: k_attn rewritten for occupancy (8 waves, online softmax halves,
// VGPR<=128, single barrier). Other kernels unchanged from round 3.
//
// ws layout (bytes):
//   [0,         33554432)  m bf16 [65536][256]      (reused as gwa after attn)
//   [33554432,  35651584)  nb f32 [8][256][256]
//   [35651584,  69206016)  q  bf16 [(b*8+h)][256 r][32 c]   (pre-scaled)
//   [69206016, 102760448)  k  bf16 [(b*8+h)][256 r][32 c]
//   [102760448,136314880)  vT bf16 [(b*8+h)][32 c][256 r]   (transposed!)
//   [136314880,169869312)  g  bf16 [(b*8+h)][256 r][32 c]   (sigmoid applied)
//   [169869312,170524672)  wT bf16 [5][256 n][256 k]  (q,k,v,gate,o transposed)
// ============================================================================

typedef unsigned short u16;
typedef unsigned int   u32;
typedef __attribute__((ext_vector_type(8))) short bf16x8;
typedef __attribute__((ext_vector_type(4))) float f32x4;

__device__ __forceinline__ float bf2f(u16 u){ union { u32 i; float f; } v; v.i = ((u32)u)<<16; return v.f; }
__device__ __forceinline__ u16 f2bf(float f){
  union { float f; u32 i; } v; v.f = f; u32 x = v.i;
  return (u16)((x + 0x7fffu + ((x>>16)&1u)) >> 16);
}
__device__ __forceinline__ u32 pk2(float a, float b){ return (u32)f2bf(a) | ((u32)f2bf(b) << 16); }

__device__ __forceinline__ void gl_lds16(const void* g, void* l){
  __builtin_amdgcn_global_load_lds(
    reinterpret_cast<const __attribute__((address_space(1))) unsigned int*>(reinterpret_cast<uintptr_t>(g)),
    reinterpret_cast<__attribute__((address_space(3))) unsigned int*>(reinterpret_cast<uintptr_t>(l)),
    16, 0, 0);
}

// ---------------------------------------------------------------------------
// K0: LayerNorm msa rows (C=256) -> m bf16. (unchanged)
// ---------------------------------------------------------------------------
__global__ __launch_bounds__(256) void k_ln_msa(
    const float* __restrict__ x, const float* __restrict__ sc,
    const float* __restrict__ of, u16* __restrict__ mo)
{
  const int lane = threadIdx.x & 63;
  const int row  = (blockIdx.x << 2) + (threadIdx.x >> 6);
  float4 v = ((const float4*)(x + (size_t)row * 256))[lane];
  float s  = v.x + v.y + v.z + v.w;
  float s2 = v.x*v.x + v.y*v.y + v.z*v.z + v.w*v.w;
  #pragma unroll
  for (int o = 32; o > 0; o >>= 1){ s += __shfl_xor(s, o); s2 += __shfl_xor(s2, o); }
  const float mu = s * (1.0f/256.0f);
  const float rs = rsqrtf(s2 * (1.0f/256.0f) - mu*mu + 1e-5f);
  float4 scv = ((const float4*)sc)[lane];
  float4 ofv = ((const float4*)of)[lane];
  u32 p0 = pk2((v.x-mu)*rs*scv.x + ofv.x, (v.y-mu)*rs*scv.y + ofv.y);
  u32 p1 = pk2((v.z-mu)*rs*scv.z + ofv.z, (v.w-mu)*rs*scv.w + ofv.w);
  ((uint2*)(mo + (size_t)row * 256))[lane] = make_uint2(p0, p1);
}

// ---------------------------------------------------------------------------
// K1: LayerNorm pair rows (Cz=128) + nb[h][q][k]. (unchanged)
// ---------------------------------------------------------------------------
__global__ __launch_bounds__(256) void k_ln_pair(
    const float* __restrict__ p, const float* __restrict__ sc,
    const float* __restrict__ of, const float* __restrict__ w2d,
    float* __restrict__ nb)
{
  const int lane = threadIdx.x & 63;
  const int row  = (blockIdx.x << 2) + (threadIdx.x >> 6);
  float2 v = ((const float2*)(p + (size_t)row * 128))[lane];
  float s = v.x + v.y, s2 = v.x*v.x + v.y*v.y;
  #pragma unroll
  for (int o = 32; o > 0; o >>= 1){ s += __shfl_xor(s, o); s2 += __shfl_xor(s2, o); }
  const float mu = s * (1.0f/128.0f);
  const float rs = rsqrtf(s2 * (1.0f/128.0f) - mu*mu + 1e-5f);
  const int c0 = lane * 2;
  const float y0 = (v.x - mu) * rs * sc[c0]     + of[c0];
  const float y1 = (v.y - mu) * rs * sc[c0 + 1] + of[c0 + 1];
  const float4* w0 = (const float4*)(w2d + c0 * 8);
  const float4* w1 = (const float4*)(w2d + (c0 + 1) * 8);
  float4 a0 = w0[0], b0 = w0[1], a1 = w1[0], b1 = w1[1];
  float ph[8];
  ph[0] = y0*a0.x + y1*a1.x; ph[1] = y0*a0.y + y1*a1.y;
  ph[2] = y0*a0.z + y1*a1.z; ph[3] = y0*a0.w + y1*a1.w;
  ph[4] = y0*b0.x + y1*b1.x; ph[5] = y0*b0.y + y1*b1.y;
  ph[6] = y0*b0.z + y1*b1.z; ph[7] = y0*b0.w + y1*b1.w;
  #pragma unroll
  for (int o = 32; o > 0; o >>= 1){
    #pragma unroll
    for (int hh = 0; hh < 8; hh++) ph[hh] += __shfl_xor(ph[hh], o);
  }
  if (lane == 0){
    #pragma unroll
    for (int hh = 0; hh < 8; hh++) nb[(size_t)hh * 65536 + row] = ph[hh];
  }
}

// ---------------------------------------------------------------------------
// K2: cast+transpose the 5 weight matrices (256x256 f32) -> wT[mat][n][k] bf16
// ---------------------------------------------------------------------------
__global__ __launch_bounds__(256) void k_cast(
    const float* __restrict__ qw, const float* __restrict__ kw,
    const float* __restrict__ vw, const float* __restrict__ gw,
    const float* __restrict__ ow, u16* __restrict__ wT)
{
  const int mt = blockIdx.x >> 4;
  const float* src = (mt == 0) ? qw : (mt == 1) ? kw : (mt == 2) ? vw : (mt == 3) ? gw : ow;
  u16* dst = wT + mt * 65536;
  const int tid = threadIdx.x;
  const int n  = ((blockIdx.x & 15) << 4) + (tid & 15);
  const int kc = tid >> 4;
  float v[16];
  #pragma unroll
  for (int kk = 0; kk < 16; kk++) v[kk] = src[(kc*16 + kk)*256 + n];
  #pragma unroll
  for (int p = 0; p < 8; p++)
    *(u32*)&dst[n*256 + kc*16 + 2*p] = pk2(v[2*p], v[2*p+1]);
}

// ---------------------------------------------------------------------------
// K3: QKVG projection GEMM (unchanged from round 3)
// ---------------------------------------------------------------------------
__global__ __launch_bounds__(256) void k_qkvg(
    const u16* __restrict__ m, const u16* __restrict__ wT, const float* __restrict__ gb,
    u16* __restrict__ qo, u16* __restrict__ ko, u16* __restrict__ vTo, u16* __restrict__ go)
{
  __shared__ __align__(16) u16 As[8192];
  __shared__ __align__(16) u16 Bs[8192];
  const int tid = threadIdx.x;
  const int w = tid >> 6, lane = tid & 63, g = lane >> 4, q16 = lane & 15;
  const int by = blockIdx.x & 7, bx = blockIdx.x >> 3;
  const int row0  = bx << 7;
  const int mat   = by >> 1;
  const int ncol0 = (by & 1) << 7;
  const u16* Wt = wT + mat * 65536;
  const int wr = w >> 1, wc = w & 1;

  const int rA  = ((tid >> 7) << 4) + (tid & 15);
  const int kgA = (tid >> 4) & 7;

  const f32x4 z4 = {0.f, 0.f, 0.f, 0.f};
  f32x4 acc[4][4];
  #pragma unroll
  for (int i = 0; i < 4; i++)
    #pragma unroll
    for (int j = 0; j < 4; j++) acc[i][j] = z4;

  #pragma unroll 1
  for (int ks = 0; ks < 4; ks++){
    const int k0 = ks << 6;
    #pragma unroll
    for (int c = 0; c < 4; c++){
      gl_lds16(m  + (size_t)(row0  + rA + c*32)*256 + k0 + kgA*8,
               (char*)As + c*4096 + w*1024);
      gl_lds16(Wt + (size_t)(ncol0 + rA + c*32)*256 + k0 + kgA*8,
               (char*)Bs + c*4096 + w*1024);
    }
    __syncthreads();
    #pragma unroll
    for (int kk = 0; kk < 2; kk++){
      bf16x8 af[4], bfr[4];
      #pragma unroll
      for (int i = 0; i < 4; i++){
        af[i]  = *(const bf16x8*)((const char*)As + (wr*4+i)*2048 + (kk*4+g)*256 + q16*16);
        bfr[i] = *(const bf16x8*)((const char*)Bs + (wc*4+i)*2048 + (kk*4+g)*256 + q16*16);
      }
      #pragma unroll
      for (int i = 0; i < 4; i++)
        #pragma unroll
        for (int j = 0; j < 4; j++)
          acc[i][j] = __builtin_amdgcn_mfma_f32_16x16x32_bf16(af[i], bfr[j], acc[i][j], 0, 0, 0);
    }
    __syncthreads();
  }

  const int b  = bx >> 1;
  const int rb = (row0 & 255) + wr*64 + 4*g;
  const int cb0 = ncol0 + wc*64 + q16;

  if (mat == 2){
    #pragma unroll
    for (int i = 0; i < 4; i++){
      const int r = rb + i*16;
      #pragma unroll
      for (int j = 0; j < 4; j++){
        const int col = cb0 + j*16;
        const int hh = col >> 5, cc = col & 31;
        u16* base = vTo + (size_t)(b*8 + hh)*8192 + cc*256 + r;
        *(u32*)base       = pk2(acc[i][j][0], acc[i][j][1]);
        *(u32*)(base + 2) = pk2(acc[i][j][2], acc[i][j][3]);
      }
    }
  } else {
    u16* O = (mat == 0) ? qo : (mat == 1) ? ko : go;
    #pragma unroll
    for (int i = 0; i < 4; i++){
      #pragma unroll
      for (int j = 0; j < 4; j++){
        const int col = cb0 + j*16;
        const int hh = col >> 5, cc = col & 31;
        f32x4 a = acc[i][j];
        if (mat == 0) a *= 0.17677669529663687f;
        #pragma unroll
        for (int v = 0; v < 4; v++){
          float x = a[v];
          if (mat == 3) x = 1.0f / (1.0f + __expf(-(x + gb[col])));
          O[(size_t)((b*8 + hh)*256 + rb + i*16 + v)*32 + cc] = f2bf(x);
        }
      }
    }
  }
}

// ---------------------------------------------------------------------------
// K4 (REWRITTEN): attention per (b,h), 512 thr / 8 waves, 32 q-rows per wave.
// Online softmax over two k=128 halves (S[8] live = 32 VGPR), O-rescale.
// K,V staged once in LDS; P roundtrip via per-wave 4KB swizzled buffer
// ([t4][q16][32k], 16B-slot xor (q16&3)); single __syncthreads total.
// __launch_bounds__(512,4): VGPR<=128 -> 4 waves/SIMD, 2 blocks/CU (65KB LDS).
// ---------------------------------------------------------------------------
__global__ __launch_bounds__(512, 4) void k_attn(
    const u16* __restrict__ qp, const u16* __restrict__ kp, const u16* __restrict__ vTp,
    const u16* __restrict__ gp, const int* __restrict__ mask, const float* __restrict__ nb,
    u16* __restrict__ gwa)
{
  __shared__ __align__(16) u16 Ksh[8192];      // [n 16][g 4][q16 16][8k]
  __shared__ __align__(16) u16 Vsh[8192];      // [ct 2][kg 32][c16 16][8k]
  __shared__ __align__(16) u16 Pb[8][2048];    // per-wave 4KB [t 4][q16 16][32k swz]
  __shared__ float maskb[256];
  const int tid = threadIdx.x;
  const int w = tid >> 6, lane = tid & 63, g = lane >> 4, q16 = lane & 15;
  const int blk = blockIdx.x, b = blk >> 3, h = blk & 7;
  const size_t tb = (size_t)blk * 8192;

  #pragma unroll
  for (int c = 0; c < 2; c++){
    gl_lds16(kp  + tb + (size_t)((c*8 + w)*16 + q16)*32 + g*8,
             (char*)Ksh + c*8192 + w*1024);
    gl_lds16(vTp + tb + (size_t)(c*16 + q16)*256 + (w*4 + g)*8,
             (char*)Vsh + c*8192 + w*1024);
  }
  if (tid < 256) maskb[tid] = 1e9f * ((float)mask[b*256 + tid] - 1.0f);
  __syncthreads();

  const float* nbh = nb + (size_t)h * 65536;
  const f32x4 z4 = {0.f,0.f,0.f,0.f};
  u16* pb = Pb[w];
  const int rsw = (g ^ (q16 & 3)) << 4;        // read-side swizzled 16B slot

  #pragma unroll 1
  for (int jj = 0; jj < 2; jj++){
    const int q = w*32 + jj*16 + q16;
    const bf16x8 qf = *(const bf16x8*)(qp + tb + (size_t)q*32 + g*8);
    f32x4 O0 = z4, O1 = z4;
    float l = 0.f, mrun = -3.0e38f;

    #pragma unroll 1
    for (int hh = 0; hh < 2; hh++){
      f32x4 S[8];
      #pragma unroll
      for (int n8 = 0; n8 < 8; n8++){
        const bf16x8 kf = *(const bf16x8*)((const char*)Ksh + (hh*8+n8)*1024 + g*256 + q16*16);
        S[n8] = __builtin_amdgcn_mfma_f32_16x16x32_bf16(kf, qf, z4, 0, 0, 0);
      }
      float hmax = -3.0e38f;
      #pragma unroll
      for (int n8 = 0; n8 < 8; n8++){
        const f32x4 nbv = *(const f32x4*)(nbh + (size_t)q*256 + (hh*8+n8)*16 + 4*g);
        const f32x4 mbv = *(const f32x4*)&maskb[(hh*8+n8)*16 + 4*g];
        S[n8] += nbv + mbv;
        hmax = fmaxf(hmax, fmaxf(fmaxf(S[n8][0],S[n8][1]), fmaxf(S[n8][2],S[n8][3])));
      }
      hmax = fmaxf(hmax, __shfl_xor(hmax, 16));
      hmax = fmaxf(hmax, __shfl_xor(hmax, 32));
      const float mnew = fmaxf(mrun, hmax);
      const float fsc = __expf(mrun - mnew);
      l *= fsc; O0 *= fsc; O1 *= fsc; mrun = mnew;

      u32 cpk[8], dpk[8];
      #pragma unroll
      for (int n8 = 0; n8 < 8; n8++){
        const float p0 = __expf(S[n8][0]-mnew), p1 = __expf(S[n8][1]-mnew);
        const float p2 = __expf(S[n8][2]-mnew), p3 = __expf(S[n8][3]-mnew);
        l += (p0+p1)+(p2+p3);
        cpk[n8] = pk2(p0,p1); dpk[n8] = pk2(p2,p3);
      }
      #pragma unroll
      for (int n8 = 0; n8 < 8; n8++){
        const int sl = (2*(n8&1) + (g>>1)) ^ (q16&3);
        *(uint2*)((char*)pb + (n8>>1)*1024 + q16*64 + sl*16 + (g&1)*8)
            = make_uint2(cpk[n8], dpk[n8]);
      }
      #pragma unroll
      for (int c4 = 0; c4 < 4; c4++){
        const bf16x8 pf = *(const bf16x8*)((const char*)pb + c4*1024 + q16*64 + rsw);
        const int kg = (hh*4 + c4)*4 + g;
        const bf16x8 v0 = *(const bf16x8*)((const char*)Vsh + kg*256 + q16*16);
        const bf16x8 v1 = *(const bf16x8*)((const char*)Vsh + 8192 + kg*256 + q16*16);
        O0 = __builtin_amdgcn_mfma_f32_16x16x32_bf16(v0, pf, O0, 0, 0, 0);
        O1 = __builtin_amdgcn_mfma_f32_16x16x32_bf16(v1, pf, O1, 0, 0, 0);
      }
    }

    l += __shfl_xor(l, 16);
    l += __shfl_xor(l, 32);
    const float inv = 1.0f / l;

    const uint2 gvA = *(const uint2*)(gp + tb + (size_t)q*32 + 4*g);
    const uint2 gvB = *(const uint2*)(gp + tb + (size_t)q*32 + 16 + 4*g);
    const float ga0 = bf2f((u16)(gvA.x & 0xffffu)), ga1 = bf2f((u16)(gvA.x >> 16));
    const float ga2 = bf2f((u16)(gvA.y & 0xffffu)), ga3 = bf2f((u16)(gvA.y >> 16));
    const float gb0 = bf2f((u16)(gvB.x & 0xffffu)), gb1 = bf2f((u16)(gvB.x >> 16));
    const float gb2 = bf2f((u16)(gvB.y & 0xffffu)), gb3 = bf2f((u16)(gvB.y >> 16));
    u16* dst = gwa + (size_t)(b*256 + q)*256 + h*32 + 4*g;
    *(u32*)dst        = pk2(O0[0]*inv*ga0, O0[1]*inv*ga1);
    *(u32*)(dst + 2)  = pk2(O0[2]*inv*ga2, O0[3]*inv*ga3);
    *(u32*)(dst + 16) = pk2(O1[0]*inv*gb0, O1[1]*inv*gb1);
    *(u32*)(dst + 18) = pk2(O1[2]*inv*gb2, O1[3]*inv*gb3);
  }
}

// ---------------------------------------------------------------------------
// K5: output projection GEMM (unchanged from round 3)
// ---------------------------------------------------------------------------
__global__ __launch_bounds__(256) void k_out(
    const u16* __restrict__ a, const u16* __restrict__ Wt, const float* __restrict__ ob,
    float* __restrict__ out)
{
  __shared__ __align__(16) u16 As[8192];
  __shared__ __align__(16) u16 Bs[8192];
  const int tid = threadIdx.x;
  const int w = tid >> 6, lane = tid & 63, g = lane >> 4, q16 = lane & 15;
  const int by = blockIdx.x & 1, bx = blockIdx.x >> 1;
  const int row0  = bx << 7;
  const int ncol0 = by << 7;
  const int wr = w >> 1, wc = w & 1;

  const int rA  = ((tid >> 7) << 4) + (tid & 15);
  const int kgA = (tid >> 4) & 7;

  const f32x4 z4 = {0.f, 0.f, 0.f, 0.f};
  f32x4 acc[4][4];
  #pragma unroll
  for (int i = 0; i < 4; i++)
    #pragma unroll
    for (int j = 0; j < 4; j++) acc[i][j] = z4;

  #pragma unroll 1
  for (int ks = 0; ks < 4; ks++){
    const int k0 = ks << 6;
    #pragma unroll
    for (int c = 0; c < 4; c++){
      gl_lds16(a  + (size_t)(row0  + rA + c*32)*256 + k0 + kgA*8,
               (char*)As + c*4096 + w*1024);
      gl_lds16(Wt + (size_t)(ncol0 + rA + c*32)*256 + k0 + kgA*8,
               (char*)Bs + c*4096 + w*1024);
    }
    __syncthreads();
    #pragma unroll
    for (int kk = 0; kk < 2; kk++){
      bf16x8 af[4], bfr[4];
      #pragma unroll
      for (int i = 0; i < 4; i++){
        af[i]  = *(const bf16x8*)((const char*)As + (wr*4+i)*2048 + (kk*4+g)*256 + q16*16);
        bfr[i] = *(const bf16x8*)((const char*)Bs + (wc*4+i)*2048 + (kk*4+g)*256 + q16*16);
      }
      #pragma unroll
      for (int i = 0; i < 4; i++)
        #pragma unroll
        for (int j = 0; j < 4; j++)
          acc[i][j] = __builtin_amdgcn_mfma_f32_16x16x32_bf16(af[i], bfr[j], acc[i][j], 0, 0, 0);
    }
    __syncthreads();
  }

  const int rb = row0 + wr*64 + 4*g;
  #pragma unroll
  for (int i = 0; i < 4; i++){
    #pragma unroll
    for (int j = 0; j < 4; j++){
      const int col = ncol0 + wc*64 + j*16 + q16;
      const float bias = ob[col];
      #pragma unroll
      for (int v = 0; v < 4; v++)
        out[(size_t)(rb + i*16 + v)*256 + col] = acc[i][j][v] + bias;
    }
  }
}

// ---------------------------------------------------------------------------
extern "C" void kernel_launch(void* const* d_in, const int* in_sizes, int n_in,
                              void* d_out, int out_size, void* d_ws, size_t ws_size,
                              hipStream_t stream)
{
  (void)in_sizes; (void)n_in; (void)out_size; (void)ws_size;
  const float* msa  = (const float*)d_in[0];
  const int*   mask = (const int*)  d_in[1];
  const float* pair = (const float*)d_in[2];
  const float* qns  = (const float*)d_in[3];
  const float* qno  = (const float*)d_in[4];
  const float* pns  = (const float*)d_in[5];
  const float* pno  = (const float*)d_in[6];
  const float* w2d  = (const float*)d_in[7];
  const float* qw   = (const float*)d_in[8];
  const float* kw   = (const float*)d_in[9];
  const float* vw   = (const float*)d_in[10];
  const float* ow   = (const float*)d_in[11];
  const float* ob   = (const float*)d_in[12];
  const float* gw   = (const float*)d_in[13];
  const float* gb   = (const float*)d_in[14];
  float* out = (float*)d_out;

  char* ws = (char*)d_ws;
  u16*   m_ws = (u16*)ws;                          // 33,554,432 B (also gwa)
  float* nb   = (float*)(ws + 33554432);           //  2,097,152 B
  u16*   q_ws = (u16*)(ws + 35651584);
  u16*   k_ws = q_ws + 16777216;
  u16*   vT_ws= k_ws + 16777216;
  u16*   g_ws = vT_ws + 16777216;
  u16*   wT   = (u16*)(ws + 169869312);            // 655,360 B
  u16*   gwa  = m_ws;

  k_ln_msa <<<16384, 256, 0, stream>>>(msa, qns, qno, m_ws);
  k_ln_pair<<<16384, 256, 0, stream>>>(pair, pns, pno, w2d, nb);
  k_cast   <<<   80, 256, 0, stream>>>(qw, kw, vw, gw, ow, wT);
  k_qkvg   <<< 4096, 256, 0, stream>>>(m_ws, wT, gb, q_ws, k_ws, vT_ws, g_ws);
  k_attn   <<< 2048, 512, 0, stream>>>(q_ws, k_ws, vT_ws, g_ws, mask, nb, gwa);
  k_out    <<< 1024, 256, 0, stream>>>(gwa, wT + 4*65536, ob, out);
}

// Round 6
// 440.248 us; speedup vs baseline: 2.6183x; 1.1117x over previous
//
#include <hip/hip_runtime.h>
#include <hip/hip_bf16.h>
#include <stdint.h>

// ============================================================================
// MSARowAttentionWithPairBias (S=256,R=256,C=256,H=8,d=32) — MI355X gfx950
// Round 5 (resubmit after GPU acquisition timeout): k_qkvg + k_out get
// (a) XCD-local grid decode (all column-blocks of an A-tile on the same XCD
// -> L2 A-reuse), (b) double-buffered 2-phase pipeline (stage next K-tile
// while computing current). k_attn unchanged.
//
// ws layout (bytes):
//   [0,         33554432)  m bf16 [65536][256]      (reused as gwa after attn)
//   [33554432,  35651584)  nb f32 [8][256][256]
//   [35651584,  69206016)  q  bf16 [(b*8+h)][256 r][32 c]   (pre-scaled)
//   [69206016, 102760448)  k  bf16 [(b*8+h)][256 r][32 c]
//   [102760448,136314880)  vT bf16 [(b*8+h)][32 c][256 r]   (transposed!)
//   [136314880,169869312)  g  bf16 [(b*8+h)][256 r][32 c]   (sigmoid applied)
//   [169869312,170524672)  wT bf16 [5][256 n][256 k]  (q,k,v,gate,o transposed)
// ============================================================================

typedef unsigned short u16;
typedef unsigned int   u32;
typedef __attribute__((ext_vector_type(8))) short bf16x8;
typedef __attribute__((ext_vector_type(4))) float f32x4;

__device__ __forceinline__ float bf2f(u16 u){ union { u32 i; float f; } v; v.i = ((u32)u)<<16; return v.f; }
__device__ __forceinline__ u16 f2bf(float f){
  union { float f; u32 i; } v; v.f = f; u32 x = v.i;
  return (u16)((x + 0x7fffu + ((x>>16)&1u)) >> 16);
}
__device__ __forceinline__ u32 pk2(float a, float b){ return (u32)f2bf(a) | ((u32)f2bf(b) << 16); }

__device__ __forceinline__ void gl_lds16(const void* g, void* l){
  __builtin_amdgcn_global_load_lds(
    reinterpret_cast<const __attribute__((address_space(1))) unsigned int*>(reinterpret_cast<uintptr_t>(g)),
    reinterpret_cast<__attribute__((address_space(3))) unsigned int*>(reinterpret_cast<uintptr_t>(l)),
    16, 0, 0);
}

// ---------------------------------------------------------------------------
// K0: LayerNorm msa rows (C=256) -> m bf16. (unchanged)
// ---------------------------------------------------------------------------
__global__ __launch_bounds__(256) void k_ln_msa(
    const float* __restrict__ x, const float* __restrict__ sc,
    const float* __restrict__ of, u16* __restrict__ mo)
{
  const int lane = threadIdx.x & 63;
  const int row  = (blockIdx.x << 2) + (threadIdx.x >> 6);
  float4 v = ((const float4*)(x + (size_t)row * 256))[lane];
  float s  = v.x + v.y + v.z + v.w;
  float s2 = v.x*v.x + v.y*v.y + v.z*v.z + v.w*v.w;
  #pragma unroll
  for (int o = 32; o > 0; o >>= 1){ s += __shfl_xor(s, o); s2 += __shfl_xor(s2, o); }
  const float mu = s * (1.0f/256.0f);
  const float rs = rsqrtf(s2 * (1.0f/256.0f) - mu*mu + 1e-5f);
  float4 scv = ((const float4*)sc)[lane];
  float4 ofv = ((const float4*)of)[lane];
  u32 p0 = pk2((v.x-mu)*rs*scv.x + ofv.x, (v.y-mu)*rs*scv.y + ofv.y);
  u32 p1 = pk2((v.z-mu)*rs*scv.z + ofv.z, (v.w-mu)*rs*scv.w + ofv.w);
  ((uint2*)(mo + (size_t)row * 256))[lane] = make_uint2(p0, p1);
}

// ---------------------------------------------------------------------------
// K1: LayerNorm pair rows (Cz=128) + nb[h][q][k]. (unchanged)
// ---------------------------------------------------------------------------
__global__ __launch_bounds__(256) void k_ln_pair(
    const float* __restrict__ p, const float* __restrict__ sc,
    const float* __restrict__ of, const float* __restrict__ w2d,
    float* __restrict__ nb)
{
  const int lane = threadIdx.x & 63;
  const int row  = (blockIdx.x << 2) + (threadIdx.x >> 6);
  float2 v = ((const float2*)(p + (size_t)row * 128))[lane];
  float s = v.x + v.y, s2 = v.x*v.x + v.y*v.y;
  #pragma unroll
  for (int o = 32; o > 0; o >>= 1){ s += __shfl_xor(s, o); s2 += __shfl_xor(s2, o); }
  const float mu = s * (1.0f/128.0f);
  const float rs = rsqrtf(s2 * (1.0f/128.0f) - mu*mu + 1e-5f);
  const int c0 = lane * 2;
  const float y0 = (v.x - mu) * rs * sc[c0]     + of[c0];
  const float y1 = (v.y - mu) * rs * sc[c0 + 1] + of[c0 + 1];
  const float4* w0 = (const float4*)(w2d + c0 * 8);
  const float4* w1 = (const float4*)(w2d + (c0 + 1) * 8);
  float4 a0 = w0[0], b0 = w0[1], a1 = w1[0], b1 = w1[1];
  float ph[8];
  ph[0] = y0*a0.x + y1*a1.x; ph[1] = y0*a0.y + y1*a1.y;
  ph[2] = y0*a0.z + y1*a1.z; ph[3] = y0*a0.w + y1*a1.w;
  ph[4] = y0*b0.x + y1*b1.x; ph[5] = y0*b0.y + y1*b1.y;
  ph[6] = y0*b0.z + y1*b1.z; ph[7] = y0*b0.w + y1*b1.w;
  #pragma unroll
  for (int o = 32; o > 0; o >>= 1){
    #pragma unroll
    for (int hh = 0; hh < 8; hh++) ph[hh] += __shfl_xor(ph[hh], o);
  }
  if (lane == 0){
    #pragma unroll
    for (int hh = 0; hh < 8; hh++) nb[(size_t)hh * 65536 + row] = ph[hh];
  }
}

// ---------------------------------------------------------------------------
// K2: cast+transpose the 5 weight matrices (256x256 f32) -> wT[mat][n][k] bf16
// ---------------------------------------------------------------------------
__global__ __launch_bounds__(256) void k_cast(
    const float* __restrict__ qw, const float* __restrict__ kw,
    const float* __restrict__ vw, const float* __restrict__ gw,
    const float* __restrict__ ow, u16* __restrict__ wT)
{
  const int mt = blockIdx.x >> 4;
  const float* src = (mt == 0) ? qw : (mt == 1) ? kw : (mt == 2) ? vw : (mt == 3) ? gw : ow;
  u16* dst = wT + mt * 65536;
  const int tid = threadIdx.x;
  const int n  = ((blockIdx.x & 15) << 4) + (tid & 15);
  const int kc = tid >> 4;
  float v[16];
  #pragma unroll
  for (int kk = 0; kk < 16; kk++) v[kk] = src[(kc*16 + kk)*256 + n];
  #pragma unroll
  for (int p = 0; p < 8; p++)
    *(u32*)&dst[n*256 + kc*16 + 2*p] = pk2(v[2*p], v[2*p+1]);
}

// ---------------------------------------------------------------------------
// K3: QKVG projection GEMM, bf16 MFMA. M=65536, N=1024(4x256), K=256.
// 128x128 tile, BK=64, 4 waves (2x2), 4x4 16x16 frags each.
// Round-5: XCD-local decode (bx%8 == blk%8 for all 8 col-blocks of a row) +
// double-buffered 2-phase K-pipeline (stage ks+1 during compute of ks).
// ---------------------------------------------------------------------------
__global__ __launch_bounds__(256) void k_qkvg(
    const u16* __restrict__ m, const u16* __restrict__ wT, const float* __restrict__ gb,
    u16* __restrict__ qo, u16* __restrict__ ko, u16* __restrict__ vTo, u16* __restrict__ go)
{
  __shared__ __align__(16) u16 As[2][8192];
  __shared__ __align__(16) u16 Bs[2][8192];
  const int tid = threadIdx.x;
  const int w = tid >> 6, lane = tid & 63, g = lane >> 4, q16 = lane & 15;
  const int blk = blockIdx.x;
  // XCD-local decode: bx = (blk[11:6] << 3) | blk[2:0], by = blk[5:3].
  // All 8 by-variants of one bx share blk%8 -> same XCD -> A-tile L2-reuse.
  const int bx = ((blk >> 6) << 3) | (blk & 7);
  const int by = (blk >> 3) & 7;
  const int row0  = bx << 7;
  const int mat   = by >> 1;
  const int ncol0 = (by & 1) << 7;
  const u16* Wt = wT + mat * 65536;
  const int wr = w >> 1, wc = w & 1;

  const int rA  = ((tid >> 7) << 4) + (tid & 15);   // stage row, + c*32
  const int kgA = (tid >> 4) & 7;                   // stage k-granule

  const f32x4 z4 = {0.f, 0.f, 0.f, 0.f};
  f32x4 acc[4][4];
  #pragma unroll
  for (int i = 0; i < 4; i++)
    #pragma unroll
    for (int j = 0; j < 4; j++) acc[i][j] = z4;

  auto STAGE = [&](int buf, int ks){
    const int k0 = ks << 6;
    #pragma unroll
    for (int c = 0; c < 4; c++){
      gl_lds16(m  + (size_t)(row0  + rA + c*32)*256 + k0 + kgA*8,
               (char*)As + buf*16384 + c*4096 + w*1024);
      gl_lds16(Wt + (size_t)(ncol0 + rA + c*32)*256 + k0 + kgA*8,
               (char*)Bs + buf*16384 + c*4096 + w*1024);
    }
  };

  STAGE(0, 0);
  __syncthreads();                     // vmcnt(0)+lgkmcnt(0)+barrier: buf0 ready

  #pragma unroll 1
  for (int ks = 0; ks < 4; ks++){
    const int cur = ks & 1;
    if (ks < 3) STAGE(cur ^ 1, ks + 1);   // prefetch overlaps compute below
    const char* Ab = (const char*)As + cur*16384;
    const char* Bb = (const char*)Bs + cur*16384;
    #pragma unroll
    for (int kk = 0; kk < 2; kk++){
      bf16x8 af[4], bfr[4];
      #pragma unroll
      for (int i = 0; i < 4; i++){
        af[i]  = *(const bf16x8*)(Ab + (wr*4+i)*2048 + (kk*4+g)*256 + q16*16);
        bfr[i] = *(const bf16x8*)(Bb + (wc*4+i)*2048 + (kk*4+g)*256 + q16*16);
      }
      #pragma unroll
      for (int i = 0; i < 4; i++)
        #pragma unroll
        for (int j = 0; j < 4; j++)
          acc[i][j] = __builtin_amdgcn_mfma_f32_16x16x32_bf16(af[i], bfr[j], acc[i][j], 0, 0, 0);
    }
    if (ks < 3) __syncthreads();       // drains prefetch; buf[cur^1] ready
  }

  const int b  = bx >> 1;
  const int rb = (row0 & 255) + wr*64 + 4*g;
  const int cb0 = ncol0 + wc*64 + q16;

  if (mat == 2){
    #pragma unroll
    for (int i = 0; i < 4; i++){
      const int r = rb + i*16;
      #pragma unroll
      for (int j = 0; j < 4; j++){
        const int col = cb0 + j*16;
        const int hh = col >> 5, cc = col & 31;
        u16* base = vTo + (size_t)(b*8 + hh)*8192 + cc*256 + r;
        *(u32*)base       = pk2(acc[i][j][0], acc[i][j][1]);
        *(u32*)(base + 2) = pk2(acc[i][j][2], acc[i][j][3]);
      }
    }
  } else {
    u16* O = (mat == 0) ? qo : (mat == 1) ? ko : go;
    #pragma unroll
    for (int i = 0; i < 4; i++){
      #pragma unroll
      for (int j = 0; j < 4; j++){
        const int col = cb0 + j*16;
        const int hh = col >> 5, cc = col & 31;
        f32x4 a = acc[i][j];
        if (mat == 0) a *= 0.17677669529663687f;
        #pragma unroll
        for (int v = 0; v < 4; v++){
          float x = a[v];
          if (mat == 3) x = 1.0f / (1.0f + __expf(-(x + gb[col])));
          O[(size_t)((b*8 + hh)*256 + rb + i*16 + v)*32 + cc] = f2bf(x);
        }
      }
    }
  }
}

// ---------------------------------------------------------------------------
// K4: attention per (b,h), 512 thr / 8 waves, 32 q-rows per wave. (unchanged)
// ---------------------------------------------------------------------------
__global__ __launch_bounds__(512, 4) void k_attn(
    const u16* __restrict__ qp, const u16* __restrict__ kp, const u16* __restrict__ vTp,
    const u16* __restrict__ gp, const int* __restrict__ mask, const float* __restrict__ nb,
    u16* __restrict__ gwa)
{
  __shared__ __align__(16) u16 Ksh[8192];      // [n 16][g 4][q16 16][8k]
  __shared__ __align__(16) u16 Vsh[8192];      // [ct 2][kg 32][c16 16][8k]
  __shared__ __align__(16) u16 Pb[8][2048];    // per-wave 4KB [t 4][q16 16][32k swz]
  __shared__ float maskb[256];
  const int tid = threadIdx.x;
  const int w = tid >> 6, lane = tid & 63, g = lane >> 4, q16 = lane & 15;
  const int blk = blockIdx.x, b = blk >> 3, h = blk & 7;
  const size_t tb = (size_t)blk * 8192;

  #pragma unroll
  for (int c = 0; c < 2; c++){
    gl_lds16(kp  + tb + (size_t)((c*8 + w)*16 + q16)*32 + g*8,
             (char*)Ksh + c*8192 + w*1024);
    gl_lds16(vTp + tb + (size_t)(c*16 + q16)*256 + (w*4 + g)*8,
             (char*)Vsh + c*8192 + w*1024);
  }
  if (tid < 256) maskb[tid] = 1e9f * ((float)mask[b*256 + tid] - 1.0f);
  __syncthreads();

  const float* nbh = nb + (size_t)h * 65536;
  const f32x4 z4 = {0.f,0.f,0.f,0.f};
  u16* pb = Pb[w];
  const int rsw = (g ^ (q16 & 3)) << 4;        // read-side swizzled 16B slot

  #pragma unroll 1
  for (int jj = 0; jj < 2; jj++){
    const int q = w*32 + jj*16 + q16;
    const bf16x8 qf = *(const bf16x8*)(qp + tb + (size_t)q*32 + g*8);
    f32x4 O0 = z4, O1 = z4;
    float l = 0.f, mrun = -3.0e38f;

    #pragma unroll 1
    for (int hh = 0; hh < 2; hh++){
      f32x4 S[8];
      #pragma unroll
      for (int n8 = 0; n8 < 8; n8++){
        const bf16x8 kf = *(const bf16x8*)((const char*)Ksh + (hh*8+n8)*1024 + g*256 + q16*16);
        S[n8] = __builtin_amdgcn_mfma_f32_16x16x32_bf16(kf, qf, z4, 0, 0, 0);
      }
      float hmax = -3.0e38f;
      #pragma unroll
      for (int n8 = 0; n8 < 8; n8++){
        const f32x4 nbv = *(const f32x4*)(nbh + (size_t)q*256 + (hh*8+n8)*16 + 4*g);
        const f32x4 mbv = *(const f32x4*)&maskb[(hh*8+n8)*16 + 4*g];
        S[n8] += nbv + mbv;
        hmax = fmaxf(hmax, fmaxf(fmaxf(S[n8][0],S[n8][1]), fmaxf(S[n8][2],S[n8][3])));
      }
      hmax = fmaxf(hmax, __shfl_xor(hmax, 16));
      hmax = fmaxf(hmax, __shfl_xor(hmax, 32));
      const float mnew = fmaxf(mrun, hmax);
      const float fsc = __expf(mrun - mnew);
      l *= fsc; O0 *= fsc; O1 *= fsc; mrun = mnew;

      u32 cpk[8], dpk[8];
      #pragma unroll
      for (int n8 = 0; n8 < 8; n8++){
        const float p0 = __expf(S[n8][0]-mnew), p1 = __expf(S[n8][1]-mnew);
        const float p2 = __expf(S[n8][2]-mnew), p3 = __expf(S[n8][3]-mnew);
        l += (p0+p1)+(p2+p3);
        cpk[n8] = pk2(p0,p1); dpk[n8] = pk2(p2,p3);
      }
      #pragma unroll
      for (int n8 = 0; n8 < 8; n8++){
        const int sl = (2*(n8&1) + (g>>1)) ^ (q16&3);
        *(uint2*)((char*)pb + (n8>>1)*1024 + q16*64 + sl*16 + (g&1)*8)
            = make_uint2(cpk[n8], dpk[n8]);
      }
      #pragma unroll
      for (int c4 = 0; c4 < 4; c4++){
        const bf16x8 pf = *(const bf16x8*)((const char*)pb + c4*1024 + q16*64 + rsw);
        const int kg = (hh*4 + c4)*4 + g;
        const bf16x8 v0 = *(const bf16x8*)((const char*)Vsh + kg*256 + q16*16);
        const bf16x8 v1 = *(const bf16x8*)((const char*)Vsh + 8192 + kg*256 + q16*16);
        O0 = __builtin_amdgcn_mfma_f32_16x16x32_bf16(v0, pf, O0, 0, 0, 0);
        O1 = __builtin_amdgcn_mfma_f32_16x16x32_bf16(v1, pf, O1, 0, 0, 0);
      }
    }

    l += __shfl_xor(l, 16);
    l += __shfl_xor(l, 32);
    const float inv = 1.0f / l;

    const uint2 gvA = *(const uint2*)(gp + tb + (size_t)q*32 + 4*g);
    const uint2 gvB = *(const uint2*)(gp + tb + (size_t)q*32 + 16 + 4*g);
    const float ga0 = bf2f((u16)(gvA.x & 0xffffu)), ga1 = bf2f((u16)(gvA.x >> 16));
    const float ga2 = bf2f((u16)(gvA.y & 0xffffu)), ga3 = bf2f((u16)(gvA.y >> 16));
    const float gb0 = bf2f((u16)(gvB.x & 0xffffu)), gb1 = bf2f((u16)(gvB.x >> 16));
    const float gb2 = bf2f((u16)(gvB.y & 0xffffu)), gb3 = bf2f((u16)(gvB.y >> 16));
    u16* dst = gwa + (size_t)(b*256 + q)*256 + h*32 + 4*g;
    *(u32*)dst        = pk2(O0[0]*inv*ga0, O0[1]*inv*ga1);
    *(u32*)(dst + 2)  = pk2(O0[2]*inv*ga2, O0[3]*inv*ga3);
    *(u32*)(dst + 16) = pk2(O1[0]*inv*gb0, O1[1]*inv*gb1);
    *(u32*)(dst + 18) = pk2(O1[2]*inv*gb2, O1[3]*inv*gb3);
  }
}

// ---------------------------------------------------------------------------
// K5: output projection GEMM. M=65536, N=256, K=256. f32 out + bias.
// Round-5: XCD-local decode + double-buffered 2-phase pipeline (as k_qkvg).
// ---------------------------------------------------------------------------
__global__ __launch_bounds__(256) void k_out(
    const u16* __restrict__ a, const u16* __restrict__ Wt, const float* __restrict__ ob,
    float* __restrict__ out)
{
  __shared__ __align__(16) u16 As[2][8192];
  __shared__ __align__(16) u16 Bs[2][8192];
  const int tid = threadIdx.x;
  const int w = tid >> 6, lane = tid & 63, g = lane >> 4, q16 = lane & 15;
  const int blk = blockIdx.x;
  // XCD-local decode: bx = (blk[9:4] << 3) | blk[2:0], by = blk[3].
  const int bx = ((blk >> 4) << 3) | (blk & 7);
  const int by = (blk >> 3) & 1;
  const int row0  = bx << 7;
  const int ncol0 = by << 7;
  const int wr = w >> 1, wc = w & 1;

  const int rA  = ((tid >> 7) << 4) + (tid & 15);
  const int kgA = (tid >> 4) & 7;

  const f32x4 z4 = {0.f, 0.f, 0.f, 0.f};
  f32x4 acc[4][4];
  #pragma unroll
  for (int i = 0; i < 4; i++)
    #pragma unroll
    for (int j = 0; j < 4; j++) acc[i][j] = z4;

  auto STAGE = [&](int buf, int ks){
    const int k0 = ks << 6;
    #pragma unroll
    for (int c = 0; c < 4; c++){
      gl_lds16(a  + (size_t)(row0  + rA + c*32)*256 + k0 + kgA*8,
               (char*)As + buf*16384 + c*4096 + w*1024);
      gl_lds16(Wt + (size_t)(ncol0 + rA + c*32)*256 + k0 + kgA*8,
               (char*)Bs + buf*16384 + c*4096 + w*1024);
    }
  };

  STAGE(0, 0);
  __syncthreads();

  #pragma unroll 1
  for (int ks = 0; ks < 4; ks++){
    const int cur = ks & 1;
    if (ks < 3) STAGE(cur ^ 1, ks + 1);
    const char* Ab = (const char*)As + cur*16384;
    const char* Bb = (const char*)Bs + cur*16384;
    #pragma unroll
    for (int kk = 0; kk < 2; kk++){
      bf16x8 af[4], bfr[4];
      #pragma unroll
      for (int i = 0; i < 4; i++){
        af[i]  = *(const bf16x8*)(Ab + (wr*4+i)*2048 + (kk*4+g)*256 + q16*16);
        bfr[i] = *(const bf16x8*)(Bb + (wc*4+i)*2048 + (kk*4+g)*256 + q16*16);
      }
      #pragma unroll
      for (int i = 0; i < 4; i++)
        #pragma unroll
        for (int j = 0; j < 4; j++)
          acc[i][j] = __builtin_amdgcn_mfma_f32_16x16x32_bf16(af[i], bfr[j], acc[i][j], 0, 0, 0);
    }
    if (ks < 3) __syncthreads();
  }

  const int rb = row0 + wr*64 + 4*g;
  #pragma unroll
  for (int i = 0; i < 4; i++){
    #pragma unroll
    for (int j = 0; j < 4; j++){
      const int col = ncol0 + wc*64 + j*16 + q16;
      const float bias = ob[col];
      #pragma unroll
      for (int v = 0; v < 4; v++)
        out[(size_t)(rb + i*16 + v)*256 + col] = acc[i][j][v] + bias;
    }
  }
}

// ---------------------------------------------------------------------------
extern "C" void kernel_launch(void* const* d_in, const int* in_sizes, int n_in,
                              void* d_out, int out_size, void* d_ws, size_t ws_size,
                              hipStream_t stream)
{
  (void)in_sizes; (void)n_in; (void)out_size; (void)ws_size;
  const float* msa  = (const float*)d_in[0];
  const int*   mask = (const int*)  d_in[1];
  const float* pair = (const float*)d_in[2];
  const float* qns  = (const float*)d_in[3];
  const float* qno  = (const float*)d_in[4];
  const float* pns  = (const float*)d_in[5];
  const float* pno  = (const float*)d_in[6];
  const float* w2d  = (const float*)d_in[7];
  const float* qw   = (const float*)d_in[8];
  const float* kw   = (const float*)d_in[9];
  const float* vw   = (const float*)d_in[10];
  const float* ow   = (const float*)d_in[11];
  const float* ob   = (const float*)d_in[12];
  const float* gw   = (const float*)d_in[13];
  const float* gb   = (const float*)d_in[14];
  float* out = (float*)d_out;

  char* ws = (char*)d_ws;
  u16*   m_ws = (u16*)ws;                          // 33,554,432 B (also gwa)
  float* nb   = (float*)(ws + 33554432);           //  2,097,152 B
  u16*   q_ws = (u16*)(ws + 35651584);
  u16*   k_ws = q_ws + 16777216;
  u16*   vT_ws= k_ws + 16777216;
  u16*   g_ws = vT_ws + 16777216;
  u16*   wT   = (u16*)(ws + 169869312);            // 655,360 B
  u16*   gwa  = m_ws;

  k_ln_msa <<<16384, 256, 0, stream>>>(msa, qns, qno, m_ws);
  k_ln_pair<<<16384, 256, 0, stream>>>(pair, pns, pno, w2d, nb);
  k_cast   <<<   80, 256, 0, stream>>>(qw, kw, vw, gw, ow, wT);
  k_qkvg   <<< 4096, 256, 0, stream>>>(m_ws, wT, gb, q_ws, k_ws, vT_ws, g_ws);
  k_attn   <<< 2048, 512, 0, stream>>>(q_ws, k_ws, vT_ws, g_ws, mask, nb, gwa);
  k_out    <<< 1024, 256, 0, stream>>>(gwa, wT + 4*65536, ob, out);
}

// Round 7
// 417.776 us; speedup vs baseline: 2.7592x; 1.0538x over previous
//
#include <hip/hip_runtime.h>
#include <hip/hip_bf16.h>
#include <stdint.h>

// ============================================================================
// MSARowAttentionWithPairBias (S=256,R=256,C=256,H=8,d=32) — MI355X gfx950
// Round 7: GEMM epilogue orientation fix (q/k/gate/out computed as C^T frags
// via mfma(B,A) -> 4 consecutive output COLS per lane -> uint2/float4 stores
// instead of 64 scalar stores) + BK=32 double-buffer (32KB LDS -> 5 blocks/CU).
// k_attn / LN / cast unchanged from round 5.
//
// ws layout (bytes):
//   [0,         33554432)  m bf16 [65536][256]      (reused as gwa after attn)
//   [33554432,  35651584)  nb f32 [8][256][256]
//   [35651584,  69206016)  q  bf16 [(b*8+h)][256 r][32 c]   (pre-scaled)
//   [69206016, 102760448)  k  bf16 [(b*8+h)][256 r][32 c]
//   [102760448,136314880)  vT bf16 [(b*8+h)][32 c][256 r]   (transposed!)
//   [136314880,169869312)  g  bf16 [(b*8+h)][256 r][32 c]   (sigmoid applied)
//   [169869312,170524672)  wT bf16 [5][256 n][256 k]  (q,k,v,gate,o transposed)
// ============================================================================

typedef unsigned short u16;
typedef unsigned int   u32;
typedef __attribute__((ext_vector_type(8))) short bf16x8;
typedef __attribute__((ext_vector_type(4))) float f32x4;

__device__ __forceinline__ float bf2f(u16 u){ union { u32 i; float f; } v; v.i = ((u32)u)<<16; return v.f; }
__device__ __forceinline__ u16 f2bf(float f){
  union { float f; u32 i; } v; v.f = f; u32 x = v.i;
  return (u16)((x + 0x7fffu + ((x>>16)&1u)) >> 16);
}
__device__ __forceinline__ u32 pk2(float a, float b){ return (u32)f2bf(a) | ((u32)f2bf(b) << 16); }

__device__ __forceinline__ void gl_lds16(const void* g, void* l){
  __builtin_amdgcn_global_load_lds(
    reinterpret_cast<const __attribute__((address_space(1))) unsigned int*>(reinterpret_cast<uintptr_t>(g)),
    reinterpret_cast<__attribute__((address_space(3))) unsigned int*>(reinterpret_cast<uintptr_t>(l)),
    16, 0, 0);
}

// ---------------------------------------------------------------------------
// K0: LayerNorm msa rows (C=256) -> m bf16. (unchanged)
// ---------------------------------------------------------------------------
__global__ __launch_bounds__(256) void k_ln_msa(
    const float* __restrict__ x, const float* __restrict__ sc,
    const float* __restrict__ of, u16* __restrict__ mo)
{
  const int lane = threadIdx.x & 63;
  const int row  = (blockIdx.x << 2) + (threadIdx.x >> 6);
  float4 v = ((const float4*)(x + (size_t)row * 256))[lane];
  float s  = v.x + v.y + v.z + v.w;
  float s2 = v.x*v.x + v.y*v.y + v.z*v.z + v.w*v.w;
  #pragma unroll
  for (int o = 32; o > 0; o >>= 1){ s += __shfl_xor(s, o); s2 += __shfl_xor(s2, o); }
  const float mu = s * (1.0f/256.0f);
  const float rs = rsqrtf(s2 * (1.0f/256.0f) - mu*mu + 1e-5f);
  float4 scv = ((const float4*)sc)[lane];
  float4 ofv = ((const float4*)of)[lane];
  u32 p0 = pk2((v.x-mu)*rs*scv.x + ofv.x, (v.y-mu)*rs*scv.y + ofv.y);
  u32 p1 = pk2((v.z-mu)*rs*scv.z + ofv.z, (v.w-mu)*rs*scv.w + ofv.w);
  ((uint2*)(mo + (size_t)row * 256))[lane] = make_uint2(p0, p1);
}

// ---------------------------------------------------------------------------
// K1: LayerNorm pair rows (Cz=128) + nb[h][q][k]. (unchanged)
// ---------------------------------------------------------------------------
__global__ __launch_bounds__(256) void k_ln_pair(
    const float* __restrict__ p, const float* __restrict__ sc,
    const float* __restrict__ of, const float* __restrict__ w2d,
    float* __restrict__ nb)
{
  const int lane = threadIdx.x & 63;
  const int row  = (blockIdx.x << 2) + (threadIdx.x >> 6);
  float2 v = ((const float2*)(p + (size_t)row * 128))[lane];
  float s = v.x + v.y, s2 = v.x*v.x + v.y*v.y;
  #pragma unroll
  for (int o = 32; o > 0; o >>= 1){ s += __shfl_xor(s, o); s2 += __shfl_xor(s2, o); }
  const float mu = s * (1.0f/128.0f);
  const float rs = rsqrtf(s2 * (1.0f/128.0f) - mu*mu + 1e-5f);
  const int c0 = lane * 2;
  const float y0 = (v.x - mu) * rs * sc[c0]     + of[c0];
  const float y1 = (v.y - mu) * rs * sc[c0 + 1] + of[c0 + 1];
  const float4* w0 = (const float4*)(w2d + c0 * 8);
  const float4* w1 = (const float4*)(w2d + (c0 + 1) * 8);
  float4 a0 = w0[0], b0 = w0[1], a1 = w1[0], b1 = w1[1];
  float ph[8];
  ph[0] = y0*a0.x + y1*a1.x; ph[1] = y0*a0.y + y1*a1.y;
  ph[2] = y0*a0.z + y1*a1.z; ph[3] = y0*a0.w + y1*a1.w;
  ph[4] = y0*b0.x + y1*b1.x; ph[5] = y0*b0.y + y1*b1.y;
  ph[6] = y0*b0.z + y1*b1.z; ph[7] = y0*b0.w + y1*b1.w;
  #pragma unroll
  for (int o = 32; o > 0; o >>= 1){
    #pragma unroll
    for (int hh = 0; hh < 8; hh++) ph[hh] += __shfl_xor(ph[hh], o);
  }
  if (lane == 0){
    #pragma unroll
    for (int hh = 0; hh < 8; hh++) nb[(size_t)hh * 65536 + row] = ph[hh];
  }
}

// ---------------------------------------------------------------------------
// K2: cast+transpose the 5 weight matrices (256x256 f32) -> wT[mat][n][k] bf16
// ---------------------------------------------------------------------------
__global__ __launch_bounds__(256) void k_cast(
    const float* __restrict__ qw, const float* __restrict__ kw,
    const float* __restrict__ vw, const float* __restrict__ gw,
    const float* __restrict__ ow, u16* __restrict__ wT)
{
  const int mt = blockIdx.x >> 4;
  const float* src = (mt == 0) ? qw : (mt == 1) ? kw : (mt == 2) ? vw : (mt == 3) ? gw : ow;
  u16* dst = wT + mt * 65536;
  const int tid = threadIdx.x;
  const int n  = ((blockIdx.x & 15) << 4) + (tid & 15);
  const int kc = tid >> 4;
  float v[16];
  #pragma unroll
  for (int kk = 0; kk < 16; kk++) v[kk] = src[(kc*16 + kk)*256 + n];
  #pragma unroll
  for (int p = 0; p < 8; p++)
    *(u32*)&dst[n*256 + kc*16 + 2*p] = pk2(v[2*p], v[2*p+1]);
}

// ---------------------------------------------------------------------------
// K3: QKVG projection GEMM, bf16 MFMA. M=65536, N=1024(4x256), K=256.
// 128x128 tile, BK=32 double-buffered (32KB LDS -> 5 blocks/CU), 4 waves.
// q/k/gate: acc = mfma(B,A) -> lane holds (row, 4 consecutive cols) -> uint2
// stores. V: acc = mfma(A,B) -> (col, 4 consecutive rows) -> vT uint2 stores.
// ---------------------------------------------------------------------------
__global__ __launch_bounds__(256) void k_qkvg(
    const u16* __restrict__ m, const u16* __restrict__ wT, const float* __restrict__ gb,
    u16* __restrict__ qo, u16* __restrict__ ko, u16* __restrict__ vTo, u16* __restrict__ go)
{
  __shared__ __align__(16) u16 As[2][4096];   // 8KB: [r/16 (8)][kg (4)][16 r][8 k]
  __shared__ __align__(16) u16 Bs[2][4096];
  const int tid = threadIdx.x;
  const int w = tid >> 6, lane = tid & 63, g = lane >> 4, q16 = lane & 15;
  const int blk = blockIdx.x;
  const int bx = ((blk >> 6) << 3) | (blk & 7);   // XCD-local decode
  const int by = (blk >> 3) & 7;
  const int row0  = bx << 7;
  const int mat   = by >> 1;
  const int ncol0 = (by & 1) << 7;
  const u16* Wt = wT + mat * 65536;
  const int wr = w >> 1, wc = w & 1;

  const f32x4 z4 = {0.f, 0.f, 0.f, 0.f};
  f32x4 acc[4][4];
  #pragma unroll
  for (int i = 0; i < 4; i++)
    #pragma unroll
    for (int j = 0; j < 4; j++) acc[i][j] = z4;

  auto STAGE = [&](int buf, int ks){
    const int k0 = ks << 5;
    #pragma unroll
    for (int c = 0; c < 2; c++){
      const int rr = (c*4 + w)*16 + q16;          // src row; src col = k0+g*8
      gl_lds16(m  + (size_t)(row0  + rr)*256 + k0 + g*8, (char*)As[buf] + (c*4+w)*1024);
      gl_lds16(Wt + (size_t)(ncol0 + rr)*256 + k0 + g*8, (char*)Bs[buf] + (c*4+w)*1024);
    }
  };

  STAGE(0, 0);
  __syncthreads();

  if (mat == 2){                                  // V: original orientation
    #pragma unroll 1
    for (int ks = 0; ks < 8; ks++){
      const int cur = ks & 1;
      if (ks < 7) STAGE(cur ^ 1, ks + 1);
      bf16x8 af[4], bfr[4];
      #pragma unroll
      for (int i = 0; i < 4; i++){
        af[i]  = *(const bf16x8*)((const char*)As[cur] + (wr*4+i)*1024 + g*256 + q16*16);
        bfr[i] = *(const bf16x8*)((const char*)Bs[cur] + (wc*4+i)*1024 + g*256 + q16*16);
      }
      #pragma unroll
      for (int i = 0; i < 4; i++)
        #pragma unroll
        for (int j = 0; j < 4; j++)
          acc[i][j] = __builtin_amdgcn_mfma_f32_16x16x32_bf16(af[i], bfr[j], acc[i][j], 0, 0, 0);
      if (ks < 7) __syncthreads();
    }
    const int b  = bx >> 1;
    const int rb = (row0 & 255) + wr*64 + 4*g;    // + i*16 + v (rows)
    const int cb0 = ncol0 + wc*64 + q16;          // + j*16    (col)
    #pragma unroll
    for (int i = 0; i < 4; i++){
      const int r = rb + i*16;
      #pragma unroll
      for (int j = 0; j < 4; j++){
        const int col = cb0 + j*16;
        const int hh = col >> 5, cc = col & 31;
        u16* base = vTo + (size_t)(b*8 + hh)*8192 + cc*256 + r;
        *(uint2*)base = make_uint2(pk2(acc[i][j][0], acc[i][j][1]),
                                   pk2(acc[i][j][2], acc[i][j][3]));
      }
    }
  } else {                                        // q/k/gate: swapped (C^T frags)
    #pragma unroll 1
    for (int ks = 0; ks < 8; ks++){
      const int cur = ks & 1;
      if (ks < 7) STAGE(cur ^ 1, ks + 1);
      bf16x8 af[4], bfr[4];
      #pragma unroll
      for (int i = 0; i < 4; i++){
        af[i]  = *(const bf16x8*)((const char*)As[cur] + (wr*4+i)*1024 + g*256 + q16*16);
        bfr[i] = *(const bf16x8*)((const char*)Bs[cur] + (wc*4+i)*1024 + g*256 + q16*16);
      }
      #pragma unroll
      for (int i = 0; i < 4; i++)
        #pragma unroll
        for (int j = 0; j < 4; j++)
          acc[i][j] = __builtin_amdgcn_mfma_f32_16x16x32_bf16(bfr[j], af[i], acc[i][j], 0, 0, 0);
      if (ks < 7) __syncthreads();
    }
    u16* O = (mat == 0) ? qo : (mat == 1) ? ko : go;
    const int b = bx >> 1;
    #pragma unroll
    for (int i = 0; i < 4; i++){
      const int row = (row0 & 255) + (wr*4 + i)*16 + q16;
      #pragma unroll
      for (int j = 0; j < 4; j++){
        const int col = ncol0 + wc*64 + j*16 + 4*g;   // + v (4 consecutive cols)
        const int hh = col >> 5, cc = col & 31;
        f32x4 a = acc[i][j];
        if (mat == 0) a *= 0.17677669529663687f;
        else if (mat == 3){
          #pragma unroll
          for (int v = 0; v < 4; v++)
            a[v] = 1.0f / (1.0f + __expf(-(a[v] + gb[col + v])));
        }
        u16* dst = O + ((size_t)(b*8 + hh)*256 + row)*32 + cc;
        *(uint2*)dst = make_uint2(pk2(a[0], a[1]), pk2(a[2], a[3]));
      }
    }
  }
}

// ---------------------------------------------------------------------------
// K4: attention per (b,h), 512 thr / 8 waves, 32 q-rows per wave. (unchanged)
// ---------------------------------------------------------------------------
__global__ __launch_bounds__(512, 4) void k_attn(
    const u16* __restrict__ qp, const u16* __restrict__ kp, const u16* __restrict__ vTp,
    const u16* __restrict__ gp, const int* __restrict__ mask, const float* __restrict__ nb,
    u16* __restrict__ gwa)
{
  __shared__ __align__(16) u16 Ksh[8192];      // [n 16][g 4][q16 16][8k]
  __shared__ __align__(16) u16 Vsh[8192];      // [ct 2][kg 32][c16 16][8k]
  __shared__ __align__(16) u16 Pb[8][2048];    // per-wave 4KB [t 4][q16 16][32k swz]
  __shared__ float maskb[256];
  const int tid = threadIdx.x;
  const int w = tid >> 6, lane = tid & 63, g = lane >> 4, q16 = lane & 15;
  const int blk = blockIdx.x, b = blk >> 3, h = blk & 7;
  const size_t tb = (size_t)blk * 8192;

  #pragma unroll
  for (int c = 0; c < 2; c++){
    gl_lds16(kp  + tb + (size_t)((c*8 + w)*16 + q16)*32 + g*8,
             (char*)Ksh + c*8192 + w*1024);
    gl_lds16(vTp + tb + (size_t)(c*16 + q16)*256 + (w*4 + g)*8,
             (char*)Vsh + c*8192 + w*1024);
  }
  if (tid < 256) maskb[tid] = 1e9f * ((float)mask[b*256 + tid] - 1.0f);
  __syncthreads();

  const float* nbh = nb + (size_t)h * 65536;
  const f32x4 z4 = {0.f,0.f,0.f,0.f};
  u16* pb = Pb[w];
  const int rsw = (g ^ (q16 & 3)) << 4;        // read-side swizzled 16B slot

  #pragma unroll 1
  for (int jj = 0; jj < 2; jj++){
    const int q = w*32 + jj*16 + q16;
    const bf16x8 qf = *(const bf16x8*)(qp + tb + (size_t)q*32 + g*8);
    f32x4 O0 = z4, O1 = z4;
    float l = 0.f, mrun = -3.0e38f;

    #pragma unroll 1
    for (int hh = 0; hh < 2; hh++){
      f32x4 S[8];
      #pragma unroll
      for (int n8 = 0; n8 < 8; n8++){
        const bf16x8 kf = *(const bf16x8*)((const char*)Ksh + (hh*8+n8)*1024 + g*256 + q16*16);
        S[n8] = __builtin_amdgcn_mfma_f32_16x16x32_bf16(kf, qf, z4, 0, 0, 0);
      }
      float hmax = -3.0e38f;
      #pragma unroll
      for (int n8 = 0; n8 < 8; n8++){
        const f32x4 nbv = *(const f32x4*)(nbh + (size_t)q*256 + (hh*8+n8)*16 + 4*g);
        const f32x4 mbv = *(const f32x4*)&maskb[(hh*8+n8)*16 + 4*g];
        S[n8] += nbv + mbv;
        hmax = fmaxf(hmax, fmaxf(fmaxf(S[n8][0],S[n8][1]), fmaxf(S[n8][2],S[n8][3])));
      }
      hmax = fmaxf(hmax, __shfl_xor(hmax, 16));
      hmax = fmaxf(hmax, __shfl_xor(hmax, 32));
      const float mnew = fmaxf(mrun, hmax);
      const float fsc = __expf(mrun - mnew);
      l *= fsc; O0 *= fsc; O1 *= fsc; mrun = mnew;

      u32 cpk[8], dpk[8];
      #pragma unroll
      for (int n8 = 0; n8 < 8; n8++){
        const float p0 = __expf(S[n8][0]-mnew), p1 = __expf(S[n8][1]-mnew);
        const float p2 = __expf(S[n8][2]-mnew), p3 = __expf(S[n8][3]-mnew);
        l += (p0+p1)+(p2+p3);
        cpk[n8] = pk2(p0,p1); dpk[n8] = pk2(p2,p3);
      }
      #pragma unroll
      for (int n8 = 0; n8 < 8; n8++){
        const int sl = (2*(n8&1) + (g>>1)) ^ (q16&3);
        *(uint2*)((char*)pb + (n8>>1)*1024 + q16*64 + sl*16 + (g&1)*8)
            = make_uint2(cpk[n8], dpk[n8]);
      }
      #pragma unroll
      for (int c4 = 0; c4 < 4; c4++){
        const bf16x8 pf = *(const bf16x8*)((const char*)pb + c4*1024 + q16*64 + rsw);
        const int kg = (hh*4 + c4)*4 + g;
        const bf16x8 v0 = *(const bf16x8*)((const char*)Vsh + kg*256 + q16*16);
        const bf16x8 v1 = *(const bf16x8*)((const char*)Vsh + 8192 + kg*256 + q16*16);
        O0 = __builtin_amdgcn_mfma_f32_16x16x32_bf16(v0, pf, O0, 0, 0, 0);
        O1 = __builtin_amdgcn_mfma_f32_16x16x32_bf16(v1, pf, O1, 0, 0, 0);
      }
    }

    l += __shfl_xor(l, 16);
    l += __shfl_xor(l, 32);
    const float inv = 1.0f / l;

    const uint2 gvA = *(const uint2*)(gp + tb + (size_t)q*32 + 4*g);
    const uint2 gvB = *(const uint2*)(gp + tb + (size_t)q*32 + 16 + 4*g);
    const float ga0 = bf2f((u16)(gvA.x & 0xffffu)), ga1 = bf2f((u16)(gvA.x >> 16));
    const float ga2 = bf2f((u16)(gvA.y & 0xffffu)), ga3 = bf2f((u16)(gvA.y >> 16));
    const float gb0 = bf2f((u16)(gvB.x & 0xffffu)), gb1 = bf2f((u16)(gvB.x >> 16));
    const float gb2 = bf2f((u16)(gvB.y & 0xffffu)), gb3 = bf2f((u16)(gvB.y >> 16));
    u16* dst = gwa + (size_t)(b*256 + q)*256 + h*32 + 4*g;
    *(u32*)dst        = pk2(O0[0]*inv*ga0, O0[1]*inv*ga1);
    *(u32*)(dst + 2)  = pk2(O0[2]*inv*ga2, O0[3]*inv*ga3);
    *(u32*)(dst + 16) = pk2(O1[0]*inv*gb0, O1[1]*inv*gb1);
    *(u32*)(dst + 18) = pk2(O1[2]*inv*gb2, O1[3]*inv*gb3);
  }
}

// ---------------------------------------------------------------------------
// K5: output projection GEMM. M=65536, N=256, K=256. f32 out + bias.
// Round-7: BK=32 double-buffer + swapped orientation -> float4 stores.
// ---------------------------------------------------------------------------
__global__ __launch_bounds__(256) void k_out(
    const u16* __restrict__ a, const u16* __restrict__ Wt, const float* __restrict__ ob,
    float* __restrict__ out)
{
  __shared__ __align__(16) u16 As[2][4096];
  __shared__ __align__(16) u16 Bs[2][4096];
  const int tid = threadIdx.x;
  const int w = tid >> 6, lane = tid & 63, g = lane >> 4, q16 = lane & 15;
  const int blk = blockIdx.x;
  const int bx = ((blk >> 4) << 3) | (blk & 7);   // XCD-local decode
  const int by = (blk >> 3) & 1;
  const int row0  = bx << 7;
  const int ncol0 = by << 7;
  const int wr = w >> 1, wc = w & 1;

  const f32x4 z4 = {0.f, 0.f, 0.f, 0.f};
  f32x4 acc[4][4];
  #pragma unroll
  for (int i = 0; i < 4; i++)
    #pragma unroll
    for (int j = 0; j < 4; j++) acc[i][j] = z4;

  auto STAGE = [&](int buf, int ks){
    const int k0 = ks << 5;
    #pragma unroll
    for (int c = 0; c < 2; c++){
      const int rr = (c*4 + w)*16 + q16;
      gl_lds16(a  + (size_t)(row0  + rr)*256 + k0 + g*8, (char*)As[buf] + (c*4+w)*1024);
      gl_lds16(Wt + (size_t)(ncol0 + rr)*256 + k0 + g*8, (char*)Bs[buf] + (c*4+w)*1024);
    }
  };

  STAGE(0, 0);
  __syncthreads();

  #pragma unroll 1
  for (int ks = 0; ks < 8; ks++){
    const int cur = ks & 1;
    if (ks < 7) STAGE(cur ^ 1, ks + 1);
    bf16x8 af[4], bfr[4];
    #pragma unroll
    for (int i = 0; i < 4; i++){
      af[i]  = *(const bf16x8*)((const char*)As[cur] + (wr*4+i)*1024 + g*256 + q16*16);
      bfr[i] = *(const bf16x8*)((const char*)Bs[cur] + (wc*4+i)*1024 + g*256 + q16*16);
    }
    #pragma unroll
    for (int i = 0; i < 4; i++)
      #pragma unroll
      for (int j = 0; j < 4; j++)
        acc[i][j] = __builtin_amdgcn_mfma_f32_16x16x32_bf16(bfr[j], af[i], acc[i][j], 0, 0, 0);
    if (ks < 7) __syncthreads();
  }

  #pragma unroll
  for (int i = 0; i < 4; i++){
    const int row = row0 + (wr*4 + i)*16 + q16;
    #pragma unroll
    for (int j = 0; j < 4; j++){
      const int col = ncol0 + wc*64 + j*16 + 4*g;
      const float4 bv = *(const float4*)&ob[col];
      f32x4 acv = acc[i][j];
      *(float4*)&out[(size_t)row*256 + col] =
          make_float4(acv[0]+bv.x, acv[1]+bv.y, acv[2]+bv.z, acv[3]+bv.w);
    }
  }
}

// ---------------------------------------------------------------------------
extern "C" void kernel_launch(void* const* d_in, const int* in_sizes, int n_in,
                              void* d_out, int out_size, void* d_ws, size_t ws_size,
                              hipStream_t stream)
{
  (void)in_sizes; (void)n_in; (void)out_size; (void)ws_size;
  const float* msa  = (const float*)d_in[0];
  const int*   mask = (const int*)  d_in[1];
  const float* pair = (const float*)d_in[2];
  const float* qns  = (const float*)d_in[3];
  const float* qno  = (const float*)d_in[4];
  const float* pns  = (const float*)d_in[5];
  const float* pno  = (const float*)d_in[6];
  const float* w2d  = (const float*)d_in[7];
  const float* qw   = (const float*)d_in[8];
  const float* kw   = (const float*)d_in[9];
  const float* vw   = (const float*)d_in[10];
  const float* ow   = (const float*)d_in[11];
  const float* ob   = (const float*)d_in[12];
  const float* gw   = (const float*)d_in[13];
  const float* gb   = (const float*)d_in[14];
  float* out = (float*)d_out;

  char* ws = (char*)d_ws;
  u16*   m_ws = (u16*)ws;                          // 33,554,432 B (also gwa)
  float* nb   = (float*)(ws + 33554432);           //  2,097,152 B
  u16*   q_ws = (u16*)(ws + 35651584);
  u16*   k_ws = q_ws + 16777216;
  u16*   vT_ws= k_ws + 16777216;
  u16*   g_ws = vT_ws + 16777216;
  u16*   wT   = (u16*)(ws + 169869312);            // 655,360 B
  u16*   gwa  = m_ws;

  k_ln_msa <<<16384, 256, 0, stream>>>(msa, qns, qno, m_ws);
  k_ln_pair<<<16384, 256, 0, stream>>>(pair, pns, pno, w2d, nb);
  k_cast   <<<   80, 256, 0, stream>>>(qw, kw, vw, gw, ow, wT);
  k_qkvg   <<< 4096, 256, 0, stream>>>(m_ws, wT, gb, q_ws, k_ws, vT_ws, g_ws);
  k_attn   <<< 2048, 512, 0, stream>>>(q_ws, k_ws, vT_ws, g_ws, mask, nb, gwa);
  k_out    <<< 1024, 256, 0, stream>>>(gwa, wT + 4*65536, ob, out);
}